// Round 6
// baseline (307.265 us; speedup 1.0000x reference)
//
#include <hip/hip_runtime.h>
#include <hip/hip_bf16.h>
#include <stdint.h>

// ---------- types ----------
typedef __bf16 v8bf __attribute__((ext_vector_type(8)));
typedef float  v4f  __attribute__((ext_vector_type(4)));

__device__ __forceinline__ ushort f2bf(float f) {
    union { float f; uint32_t u; } x; x.f = f;
    uint32_t r = (x.u + 0x7FFFu + ((x.u >> 16) & 1u)) >> 16;
    return (ushort)r;
}
// pack two non-negative floats to bf16x2 (round-half-up): 2 add + 1 v_perm
__device__ __forceinline__ uint32_t pack2bf(float a, float b) {
    union { float f; uint32_t u; } xa, xb; xa.f = a; xb.f = b;
    return __builtin_amdgcn_perm(xb.u + 0x8000u, xa.u + 0x8000u, 0x07060302u);
}

__device__ __forceinline__ void load_lds16(const void* g, void* l) {
    __builtin_amdgcn_global_load_lds(
        (const __attribute__((address_space(1))) uint32_t*)g,
        (__attribute__((address_space(3))) uint32_t*)l, 16, 0, 0);
}

// phase barrier: raw s_barrier (NO implicit vmcnt(0) drain, unlike __syncthreads)
__device__ __forceinline__ void pbar() {
    __builtin_amdgcn_sched_barrier(0);
    __builtin_amdgcn_s_barrier();
    __builtin_amdgcn_sched_barrier(0);
}
template <int N>
__device__ __forceinline__ void vmwait() {
    if constexpr (N == 0)      asm volatile("s_waitcnt vmcnt(0)" ::: "memory");
    else if constexpr (N == 3) asm volatile("s_waitcnt vmcnt(3)" ::: "memory");
    else                       asm volatile("s_waitcnt vmcnt(4)" ::: "memory");
    __builtin_amdgcn_sched_barrier(0);
}

// ---------- elementwise convert ----------
__global__ void cvt_f32_bf16_k(const float4* __restrict__ src,
                               ushort* __restrict__ dst, int n4) {
    int i = blockIdx.x * 256 + threadIdx.x;
    if (i >= n4) return;
    float4 f = src[i];
    ushort4 u = make_ushort4(f2bf(f.x), f2bf(f.y), f2bf(f.z), f2bf(f.w));
    *(ushort4*)(dst + 4 * (size_t)i) = u;
}

// ---------- fused LDS-tiled transpose+convert for all 4 weights ----------
__global__ __launch_bounds__(256) void transpose_all(
    const float* __restrict__ Wq, const float* __restrict__ Wk,
    const float* __restrict__ Wv, const float* __restrict__ Wo,
    ushort* __restrict__ wqk_t, ushort* __restrict__ wv_t,
    ushort* __restrict__ wo_t) {
    __shared__ ushort tile[64][65];
    const int tid = threadIdx.x;
    const int ix = blockIdx.x, k0 = blockIdx.y * 64;
    const float* src; ushort* dst; int N, n0;
    if (ix < 32)      { src = Wq; dst = wqk_t;                       N = 2048; n0 = ix * 64; }
    else if (ix < 40) { src = Wk; dst = wqk_t + (size_t)2048 * 2048; N = 512;  n0 = (ix - 32) * 64; }
    else if (ix < 48) { src = Wv; dst = wv_t;                        N = 512;  n0 = (ix - 40) * 64; }
    else              { src = Wo; dst = wo_t;                        N = 2048; n0 = (ix - 48) * 64; }
    const int nn = tid & 63, kb = tid >> 6;
#pragma unroll
    for (int p = 0; p < 16; ++p) {
        int kk = p * 4 + kb;
        tile[kk][nn] = f2bf(src[(size_t)(k0 + kk) * N + n0 + nn]);
    }
    __syncthreads();
    const int nr = tid >> 2, kch = (tid & 3) * 16;
    union { ushort u[16]; uint4 q[2]; } tmp;
#pragma unroll
    for (int j = 0; j < 16; ++j) tmp.u[j] = tile[kch + j][nr];
    uint4* out = (uint4*)&dst[(size_t)(n0 + nr) * 2048 + k0 + kch];
    out[0] = tmp.q[0];
    out[1] = tmp.q[1];
}

// ---------- 256x256 8-phase GEMM (T2+T3+T4+T5), K = 2048 ----------
template <bool OUT_BF16>
__device__ __forceinline__ void gemm256_body(
    const ushort* __restrict__ A, const ushort* __restrict__ Bt,
    void* __restrict__ Cout, int ldc, int m0, int n0,
    ushort* As, ushort* Bs) {
    constexpr int K   = 2048;
    constexpr int NKT = K / 64;
    constexpr int VMK = 4;              // in-flight allowance = loads per kh (A2+B2)

    const int tid  = threadIdx.x;
    const int wv   = tid >> 6, lane = tid & 63;
    const int wr   = wv >> 2,  wc   = wv & 3;
    const int mq   = lane & 15, quad = lane >> 4;
    const int cho  = ((quad ^ (mq & 3)) << 3);

    const int srow = tid >> 2;
    const int cxr  = (((tid & 3) ^ (srow & 3)) << 3);
    const ushort* sA0 = A  + (size_t)(m0 + srow) * K + cxr;
    const ushort* sA1 = sA0 + (size_t)128 * K;
    const ushort* sB0 = Bt + (size_t)(n0 + srow) * K + cxr;
    const ushort* sB1 = sB0 + (size_t)128 * K;
    const int sdo = wv * 512;

    const int arow = wr * 128 + mq;
    const int brow = wc * 64 + mq;

    v4f acc[8][4] = {};

    auto stageA = [&](int buf, int kh, int kt) {
        const int ko = kt * 64 + kh * 32;
        ushort* d = As + (buf * 2 + kh) * 8192 + sdo;
        load_lds16(sA0 + ko, d);
        load_lds16(sA1 + ko, d + 4096);
    };
    auto stageB = [&](int buf, int kh, int kt) {
        const int ko = kt * 64 + kh * 32;
        ushort* d = Bs + (buf * 2 + kh) * 8192 + sdo;
        load_lds16(sB0 + ko, d);
        load_lds16(sB1 + ko, d + 4096);
    };
    auto rdA = [&](v8bf (&r)[4], const ushort* kb, int r0) {
#pragma unroll
        for (int i = 0; i < 4; ++i)
            r[i] = *(const v8bf*)&kb[(r0 + i * 16) * 32 + cho];
    };
    auto rdB = [&](v8bf (&r)[4], const ushort* kb) {
#pragma unroll
        for (int i = 0; i < 4; ++i)
            r[i] = *(const v8bf*)&kb[(brow + i * 16) * 32 + cho];
    };
    auto mma = [&](int mtb, const v8bf (&a)[4], const v8bf (&b)[4]) {
#pragma unroll
        for (int i = 0; i < 4; ++i)
#pragma unroll
            for (int nt = 0; nt < 4; ++nt)
                acc[mtb + i][nt] = __builtin_amdgcn_mfma_f32_16x16x32_bf16(
                    a[i], b[nt], acc[mtb + i][nt], 0, 0, 0);
    };

    stageA(0, 0, 0); stageB(0, 0, 0); stageA(0, 1, 0); stageB(0, 1, 0);
    vmwait<VMK>();
    __builtin_amdgcn_s_barrier();
    __builtin_amdgcn_sched_barrier(0);

#pragma unroll 1
    for (int t = 0; t < NKT; ++t) {
        const int p = t & 1, pn = p ^ 1;
        const bool more = (t + 1 < NKT);
        const ushort* a0 = As + p * 16384;
        const ushort* a1 = a0 + 8192;
        const ushort* b0 = Bs + p * 16384;
        const ushort* b1 = b0 + 8192;
        v8bf af[4], bfr[4];

        rdA(af, a0, arow); rdB(bfr, b0);
        if (more) stageA(pn, 0, t + 1);
        pbar();
        __builtin_amdgcn_s_setprio(1); mma(0, af, bfr); __builtin_amdgcn_s_setprio(0);
        pbar();
        rdA(af, a0, arow + 64);
        if (more) stageB(pn, 0, t + 1);
        pbar();
        __builtin_amdgcn_s_setprio(1); mma(4, af, bfr); __builtin_amdgcn_s_setprio(0);
        if (more) vmwait<VMK>(); else vmwait<0>();
        pbar();
        rdA(af, a1, arow); rdB(bfr, b1);
        if (more) stageA(pn, 1, t + 1);
        pbar();
        __builtin_amdgcn_s_setprio(1); mma(0, af, bfr); __builtin_amdgcn_s_setprio(0);
        pbar();
        rdA(af, a1, arow + 64);
        if (more) stageB(pn, 1, t + 1);
        pbar();
        __builtin_amdgcn_s_setprio(1); mma(4, af, bfr); __builtin_amdgcn_s_setprio(0);
        if (more) vmwait<VMK>();
        pbar();
    }

#pragma unroll
    for (int mt = 0; mt < 8; ++mt) {
        const int r = m0 + wr * 128 + mt * 16 + quad * 4;
#pragma unroll
        for (int nt = 0; nt < 4; ++nt) {
            const int c = n0 + wc * 64 + nt * 16 + mq;
#pragma unroll
            for (int reg = 0; reg < 4; ++reg) {
                if (OUT_BF16)
                    ((ushort*)Cout)[(size_t)(r + reg) * ldc + c] = f2bf(acc[mt][nt][reg]);
                else
                    ((float*)Cout)[(size_t)(r + reg) * ldc + c] = acc[mt][nt][reg];
            }
        }
    }
}

// ---------- 128x256 8-phase GEMM (full 256-block grid for gemm_out) ----------
template <bool OUT_BF16>
__device__ __forceinline__ void gemm128_body(
    const ushort* __restrict__ A, const ushort* __restrict__ Bt,
    void* __restrict__ Cout, int ldc, int m0, int n0,
    ushort* As, ushort* Bs) {
    constexpr int K   = 2048;
    constexpr int NKT = K / 64;

    const int tid  = threadIdx.x;
    const int wv   = tid >> 6, lane = tid & 63;
    const int wr   = wv >> 2,  wc   = wv & 3;
    const int mq   = lane & 15, quad = lane >> 4;
    const int cho  = ((quad ^ (mq & 3)) << 3);

    const int srow = tid >> 2;
    const int cxr  = (((tid & 3) ^ (srow & 3)) << 3);
    const ushort* sA0 = A  + (size_t)(m0 + srow) * K + cxr;
    const ushort* sB0 = Bt + (size_t)(n0 + srow) * K + cxr;
    const ushort* sB1 = sB0 + (size_t)128 * K;
    const int sdo = wv * 512;

    const int arow = wr * 64 + mq;
    const int brow = wc * 64 + mq;

    v4f acc[4][4] = {};

    auto stage = [&](int buf, int kh, int kt) {   // A(1) + B(2) loads per kh
        const int ko = kt * 64 + kh * 32;
        load_lds16(sA0 + ko, As + (buf * 2 + kh) * 4096 + sdo);
        ushort* d = Bs + (buf * 2 + kh) * 8192 + sdo;
        load_lds16(sB0 + ko, d);
        load_lds16(sB1 + ko, d + 4096);
    };
    auto rd4 = [&](v8bf (&r)[4], const ushort* kb, int r0) {
#pragma unroll
        for (int i = 0; i < 4; ++i)
            r[i] = *(const v8bf*)&kb[(r0 + i * 16) * 32 + cho];
    };
    auto mma = [&](const v8bf (&a)[4], const v8bf (&b)[4]) {
#pragma unroll
        for (int i = 0; i < 4; ++i)
#pragma unroll
            for (int nt = 0; nt < 4; ++nt)
                acc[i][nt] = __builtin_amdgcn_mfma_f32_16x16x32_bf16(
                    a[i], b[nt], acc[i][nt], 0, 0, 0);
    };

    stage(0, 0, 0); stage(0, 1, 0);
    vmwait<3>();
    __builtin_amdgcn_s_barrier();
    __builtin_amdgcn_sched_barrier(0);

#pragma unroll 1
    for (int t = 0; t < NKT; ++t) {
        const int p = t & 1, pn = p ^ 1;
        const bool more = (t + 1 < NKT);
        const ushort* a0 = As + p * 8192;
        const ushort* a1 = a0 + 4096;
        const ushort* b0 = Bs + p * 16384;
        const ushort* b1 = b0 + 8192;
        v8bf af[4], bfr[4];

        // kh0 phase
        rd4(af, a0, arow); rd4(bfr, b0, brow);
        if (more) stage(pn, 0, t + 1);
        pbar();
        __builtin_amdgcn_s_setprio(1); mma(af, bfr); __builtin_amdgcn_s_setprio(0);
        if (more) vmwait<3>(); else vmwait<0>();
        pbar();
        // kh1 phase
        rd4(af, a1, arow); rd4(bfr, b1, brow);
        if (more) stage(pn, 1, t + 1);
        pbar();
        __builtin_amdgcn_s_setprio(1); mma(af, bfr); __builtin_amdgcn_s_setprio(0);
        if (more) vmwait<3>();
        pbar();
    }

#pragma unroll
    for (int mt = 0; mt < 4; ++mt) {
        const int r = m0 + wr * 64 + mt * 16 + quad * 4;
#pragma unroll
        for (int nt = 0; nt < 4; ++nt) {
            const int c = n0 + wc * 64 + nt * 16 + mq;
#pragma unroll
            for (int reg = 0; reg < 4; ++reg) {
                if (OUT_BF16)
                    ((ushort*)Cout)[(size_t)(r + reg) * ldc + c] = f2bf(acc[mt][nt][reg]);
                else
                    ((float*)Cout)[(size_t)(r + reg) * ldc + c] = acc[mt][nt][reg];
            }
        }
    }
}

// fused QK-projection (160 blocks) + V^T-projection (32 blocks)
__global__ __launch_bounds__(512, 2) void gemm_qkv(
    const ushort* __restrict__ xb, const ushort* __restrict__ wqk_t,
    const ushort* __restrict__ wv_t, ushort* __restrict__ qkb,
    ushort* __restrict__ vtb) {
    __shared__ __align__(16) ushort As[32768];   // 64 KB
    __shared__ __align__(16) ushort Bs[32768];   // 64 KB
    int w = (blockIdx.x & 7) * 24 + (blockIdx.x >> 3);   // XCD-chunked (192 = 8*24)
    const ushort *Ap, *Bp; ushort* Cp; int ldc, m0, n0;
    if (w < 160) {   // qkb[4096][2560] = xb * wqk_t^T
        Ap = xb; Bp = wqk_t; Cp = qkb; ldc = 2560;
        m0 = (w / 10) * 256; n0 = (w % 10) * 256;
    } else {         // vtb[512][4096] = wv_t * xb^T
        w -= 160;
        Ap = wv_t; Bp = xb; Cp = vtb; ldc = 4096;
        m0 = (w >> 4) * 256; n0 = (w & 15) * 256;
    }
    gemm256_body<true>(Ap, Bp, Cp, ldc, m0, n0, As, Bs);
}

// output projection: d_out[4096][2048] f32 = attn_out * wo_t^T
// 128x256 tiles -> 32x8 = 256 blocks = exactly 1/CU, 16 MFMA/phase
__global__ __launch_bounds__(512, 2) void gemm_out(
    const ushort* __restrict__ A, const ushort* __restrict__ Bt,
    float* __restrict__ C) {
    __shared__ __align__(16) ushort As[16384];   // 32 KB
    __shared__ __align__(16) ushort Bs[32768];   // 64 KB
    const int w = (blockIdx.x & 7) * 32 + (blockIdx.x >> 3);   // 256 = 8*32
    gemm128_body<false>(A, Bt, C, 2048, (w >> 3) * 128, (w & 7) * 256, As, Bs);
}

// ---------- flash attention v11: 4 q-groups/wave (64 rows), 256-row q-tiles ----------
// Each K/V LDS fragment now feeds 4 MFMAs (was 2); per-CU barrier rounds 68 -> 36;
// K/V HBM re-reads halve. Groups processed in PAIRS to bound live VGPRs (~200,
// no min-waves launch bound -> compiler must not spill; tripwire = WRITE_SIZE).
constexpr float SC2 = 0.18033688011f;   // 0.125 * log2(e)
constexpr float MB2 = 14.4269504089f;   // 10 * log2(e)  (fixed softmax max M=10, exact)

template <bool MASK>
__device__ __forceinline__ void attn_compute4(
    int kv0, int qrow, int mq, int quad, int lane_lo,
    const ushort* Ks, const ushort* Vs, const v8bf ones,
    const v8bf (&qf)[4][2], v4f (&oacc)[4][4], v4f (&osum)[4]) {
    const bool hi = quad >= 2;
    const int swz = mq & 7;
#pragma unroll
    for (int half = 0; half < 2; ++half) {
        uint32_t pk[4][2][2];   // [group][nt-within-half][dword]
#pragma unroll
        for (int ntl = 0; ntl < 2; ++ntl) {
            const int nt = 2 * half + ntl;
            const v8bf kb0 = *(const v8bf*)&Ks[(nt * 16 + mq) * 64 + ((quad) ^ swz) * 8];
            const v8bf kb1 = *(const v8bf*)&Ks[(nt * 16 + mq) * 64 + ((4 + quad) ^ swz) * 8];
#pragma unroll
            for (int gp = 0; gp < 2; ++gp) {   // group pairs {0,1},{2,3}
                v4f sacc[2] = {{0.f,0.f,0.f,0.f}, {0.f,0.f,0.f,0.f}};
                sacc[0] = __builtin_amdgcn_mfma_f32_16x16x32_bf16(kb0, qf[2*gp  ][0], sacc[0], 0, 0, 0);
                sacc[1] = __builtin_amdgcn_mfma_f32_16x16x32_bf16(kb0, qf[2*gp+1][0], sacc[1], 0, 0, 0);
                sacc[0] = __builtin_amdgcn_mfma_f32_16x16x32_bf16(kb1, qf[2*gp  ][1], sacc[0], 0, 0, 0);
                sacc[1] = __builtin_amdgcn_mfma_f32_16x16x32_bf16(kb1, qf[2*gp+1][1], sacc[1], 0, 0, 0);
#pragma unroll
                for (int gl = 0; gl < 2; ++gl) {
                    const int g = 2 * gp + gl;
                    float pr[4];
#pragma unroll
                    for (int reg = 0; reg < 4; ++reg) {
                        float s = sacc[gl][reg];
                        if (MASK) {
                            const int kv = kv0 + nt * 16 + quad * 4 + reg;
                            const int q  = qrow + 16 * g + mq;
                            if (kv > q) s = -3.0e38f;
                        }
                        pr[reg] = __builtin_amdgcn_exp2f(fmaf(s, SC2, -MB2));
                    }
                    pk[g][ntl][0] = pack2bf(pr[0], pr[1]);
                    pk[g][ntl][1] = pack2bf(pr[2], pr[3]);
                }
            }
        }
        // P C-layout -> A-layout via cross-quad shuffles
        v8bf pf[4];
#pragma unroll
        for (int g = 0; g < 4; ++g) {
            uint32_t a0 = __shfl(pk[g][0][0], lane_lo);
            uint32_t b0 = __shfl(pk[g][1][0], lane_lo);
            uint32_t a1 = __shfl(pk[g][0][1], lane_lo);
            uint32_t b1 = __shfl(pk[g][1][1], lane_lo);
            uint32_t a2 = __shfl(pk[g][0][0], lane_lo + 16);
            uint32_t b2 = __shfl(pk[g][1][0], lane_lo + 16);
            uint32_t a3 = __shfl(pk[g][0][1], lane_lo + 16);
            uint32_t b3 = __shfl(pk[g][1][1], lane_lo + 16);
            union { uint32_t d[4]; v8bf v; } u;
            u.d[0] = hi ? b0 : a0;
            u.d[1] = hi ? b1 : a1;
            u.d[2] = hi ? b2 : a2;
            u.d[3] = hi ? b3 : a3;
            pf[g] = u.v;
            osum[g] = __builtin_amdgcn_mfma_f32_16x16x32_bf16(pf[g], ones, osum[g], 0, 0, 0);
        }
        // PV: vb shared across all 4 groups
#pragma unroll
        for (int hdt = 0; hdt < 4; ++hdt) {
            const v8bf vb = *(const v8bf*)&Vs[(hdt * 16 + mq) * 64 + (((half << 2) + quad) ^ swz) * 8];
#pragma unroll
            for (int g = 0; g < 4; ++g)
                oacc[g][hdt] = __builtin_amdgcn_mfma_f32_16x16x32_bf16(pf[g], vb, oacc[g][hdt], 0, 0, 0);
        }
    }
}

// qkb: [B*T][2560] bf16 (Q|K); vt: [512][4096] bf16; out: [B*T][2048] bf16
// 256 threads / 4 waves / 256-row q-tiles (64 rows = 4 groups per wave).
// Grid 512 = 2/CU; same-CU pair {i, i+256} -> qt + (7-qt): per-CU tiles = 36 const.
__global__ __launch_bounds__(256) void attn_fwd(
    const ushort* __restrict__ qkb, const ushort* __restrict__ vt,
    ushort* __restrict__ outp) {
    __shared__ __align__(16) ushort Ks[2][4096];
    __shared__ __align__(16) ushort Vs[2][4096];

    const int tid  = threadIdx.x;
    const int wv   = tid >> 6, lane = tid & 63;
    const int mq = lane & 15, quad = lane >> 4;
    const int lane_lo = (quad & 1) * 32 + mq;

    const int i = blockIdx.x;
    const int u = i & 255, s = i >> 8;     // s in {0,1}
    const int h = u & 31, j = u >> 5;      // j in [0,8)
    const int b = s;
    const int qt = s ? (7 - j) : j;
    const int g = h >> 2;
    const int qb0  = qt * 256;
    const int qrow = qb0 + wv * 64;        // wave's 64 rows: 4 groups at +0,16,32,48

    union { ushort u[8]; v8bf v; } one_u;
#pragma unroll
    for (int ii = 0; ii < 8; ++ii) one_u.u[ii] = 0x3F80;
    const v8bf ones = one_u.v;

    v8bf qf[4][2];
#pragma unroll
    for (int gg = 0; gg < 4; ++gg) {
        const ushort* qp = qkb + (size_t)(b * 2048 + qrow + 16 * gg + mq) * 2560 + h * 64 + quad * 8;
        qf[gg][0] = *(const v8bf*)qp;
        qf[gg][1] = *(const v8bf*)(qp + 32);
    }

    v4f oacc[4][4] = {};
    v4f osum[4] = {};

    const ushort* kg = qkb + (size_t)(b * 2048) * 2560 + 2048 + g * 64;
    const ushort* vg = vt + (size_t)(g * 64) * 4096 + b * 2048;

    const int sr = lane >> 3;
    const int gc = (lane & 7) ^ sr;
    const ushort* kb0 = kg + (size_t)(wv * 16 + sr) * 2560 + gc * 8;
    const ushort* kb1 = kb0 + (size_t)8 * 2560;
    const ushort* vb0 = vg + (size_t)(wv * 16 + sr) * 4096 + gc * 8;
    const ushort* vb1 = vb0 + (size_t)8 * 4096;
    const int ldso = wv * 1024;

    const int ntiles = 4 * qt + 4;

    load_lds16(kb0, &Ks[0][ldso]);
    load_lds16(kb1, &Ks[0][ldso + 512]);
    load_lds16(vb0, &Vs[0][ldso]);
    load_lds16(vb1, &Vs[0][ldso + 512]);
    __syncthreads();

#pragma unroll 1
    for (int jt = 0; jt < ntiles; ++jt) {
        const int kv0 = jt * 64;
        const int p = jt & 1;
        if (jt + 1 < ntiles) {
            const int nk = kv0 + 64;
            load_lds16(kb0 + (size_t)nk * 2560, &Ks[p ^ 1][ldso]);
            load_lds16(kb1 + (size_t)nk * 2560, &Ks[p ^ 1][ldso + 512]);
            load_lds16(vb0 + nk, &Vs[p ^ 1][ldso]);
            load_lds16(vb1 + nk, &Vs[p ^ 1][ldso + 512]);
        }
        // kv0, qrow both multiples of 64: active iff kv0 <= qrow;
        // masked iff kv0 == qrow (exactly one tile per wave).
        if (kv0 <= qrow) {
            if (kv0 == qrow)
                attn_compute4<true>(kv0, qrow, mq, quad, lane_lo, Ks[p], Vs[p], ones, qf, oacc, osum);
            else
                attn_compute4<false>(kv0, qrow, mq, quad, lane_lo, Ks[p], Vs[p], ones, qf, oacc, osum);
        }
        __syncthreads();
    }

#pragma unroll
    for (int gg = 0; gg < 4; ++gg) {
#pragma unroll
        for (int reg = 0; reg < 4; ++reg) {
            const float invr = 1.0f / osum[gg][reg];
            const int rr = qrow + 16 * gg + quad * 4 + reg;
#pragma unroll
            for (int hdt = 0; hdt < 4; ++hdt)
                outp[(size_t)(b * 2048 + rr) * 2048 + h * 64 + hdt * 16 + mq] =
                    f2bf(oacc[gg][hdt][reg] * invr);
        }
    }
}

// ---------- launch ----------
extern "C" void kernel_launch(void* const* d_in, const int* in_sizes, int n_in,
                              void* d_out, int out_size, void* d_ws, size_t ws_size,
                              hipStream_t stream) {
    const float* x  = (const float*)d_in[0];
    const float* Wq = (const float*)d_in[1];
    const float* Wk = (const float*)d_in[2];
    const float* Wv = (const float*)d_in[3];
    const float* Wo = (const float*)d_in[4];

    char* ws = (char*)d_ws;
    ushort* xb    = (ushort*)(ws);                  // [4096][2048] x bf16; later attn output
    ushort* wqk_t = (ushort*)(ws + 16777216);       // [2560][2048]
    ushort* wv_t  = (ushort*)(ws + 27262976);       // [512][2048]
    ushort* wo_t  = (ushort*)(ws + 29360128);       // [2048][2048]
    ushort* qkb   = (ushort*)(ws + 37748736);       // [4096][2560]  Q|K
    ushort* vtb   = (ushort*)(ws + 58720256);       // [512][4096]   V^T

    cvt_f32_bf16_k<<<8192, 256, 0, stream>>>((const float4*)x, xb, 2097152);
    transpose_all<<<dim3(80, 32), 256, 0, stream>>>(Wq, Wk, Wv, Wo, wqk_t, wv_t, wo_t);

    gemm_qkv<<<192, 512, 0, stream>>>(xb, wqk_t, wv_t, qkb, vtb);
    attn_fwd<<<512, 256, 0, stream>>>(qkb, vtb, xb);
    gemm_out<<<256, 512, 0, stream>>>(xb, wo_t, (float*)d_out);
}

// Round 7
// 291.063 us; speedup vs baseline: 1.0557x; 1.0557x over previous
//
#include <hip/hip_runtime.h>
#include <hip/hip_bf16.h>
#include <stdint.h>

// ---------- types ----------
typedef __bf16 v8bf __attribute__((ext_vector_type(8)));
typedef float  v4f  __attribute__((ext_vector_type(4)));

__device__ __forceinline__ ushort f2bf(float f) {
    union { float f; uint32_t u; } x; x.f = f;
    uint32_t r = (x.u + 0x7FFFu + ((x.u >> 16) & 1u)) >> 16;
    return (ushort)r;
}
// pack two non-negative floats to bf16x2 (round-half-up): 2 add + 1 v_perm
__device__ __forceinline__ uint32_t pack2bf(float a, float b) {
    union { float f; uint32_t u; } xa, xb; xa.f = a; xb.f = b;
    return __builtin_amdgcn_perm(xb.u + 0x8000u, xa.u + 0x8000u, 0x07060302u);
}

__device__ __forceinline__ void load_lds16(const void* g, void* l) {
    __builtin_amdgcn_global_load_lds(
        (const __attribute__((address_space(1))) uint32_t*)g,
        (__attribute__((address_space(3))) uint32_t*)l, 16, 0, 0);
}

// phase barrier: raw s_barrier (NO implicit vmcnt(0) drain, unlike __syncthreads)
__device__ __forceinline__ void pbar() {
    __builtin_amdgcn_sched_barrier(0);
    __builtin_amdgcn_s_barrier();
    __builtin_amdgcn_sched_barrier(0);
}
template <int N>
__device__ __forceinline__ void vmwait() {
    if constexpr (N == 0)      asm volatile("s_waitcnt vmcnt(0)" ::: "memory");
    else if constexpr (N == 3) asm volatile("s_waitcnt vmcnt(3)" ::: "memory");
    else                       asm volatile("s_waitcnt vmcnt(4)" ::: "memory");
    __builtin_amdgcn_sched_barrier(0);
}

// ---------- elementwise convert ----------
__global__ void cvt_f32_bf16_k(const float4* __restrict__ src,
                               ushort* __restrict__ dst, int n4) {
    int i = blockIdx.x * 256 + threadIdx.x;
    if (i >= n4) return;
    float4 f = src[i];
    ushort4 u = make_ushort4(f2bf(f.x), f2bf(f.y), f2bf(f.z), f2bf(f.w));
    *(ushort4*)(dst + 4 * (size_t)i) = u;
}

// ---------- fused LDS-tiled transpose+convert for all 4 weights ----------
__global__ __launch_bounds__(256) void transpose_all(
    const float* __restrict__ Wq, const float* __restrict__ Wk,
    const float* __restrict__ Wv, const float* __restrict__ Wo,
    ushort* __restrict__ wqk_t, ushort* __restrict__ wv_t,
    ushort* __restrict__ wo_t) {
    __shared__ ushort tile[64][65];
    const int tid = threadIdx.x;
    const int ix = blockIdx.x, k0 = blockIdx.y * 64;
    const float* src; ushort* dst; int N, n0;
    if (ix < 32)      { src = Wq; dst = wqk_t;                       N = 2048; n0 = ix * 64; }
    else if (ix < 40) { src = Wk; dst = wqk_t + (size_t)2048 * 2048; N = 512;  n0 = (ix - 32) * 64; }
    else if (ix < 48) { src = Wv; dst = wv_t;                        N = 512;  n0 = (ix - 40) * 64; }
    else              { src = Wo; dst = wo_t;                        N = 2048; n0 = (ix - 48) * 64; }
    const int nn = tid & 63, kb = tid >> 6;
#pragma unroll
    for (int p = 0; p < 16; ++p) {
        int kk = p * 4 + kb;
        tile[kk][nn] = f2bf(src[(size_t)(k0 + kk) * N + n0 + nn]);
    }
    __syncthreads();
    const int nr = tid >> 2, kch = (tid & 3) * 16;
    union { ushort u[16]; uint4 q[2]; } tmp;
#pragma unroll
    for (int j = 0; j < 16; ++j) tmp.u[j] = tile[kch + j][nr];
    uint4* out = (uint4*)&dst[(size_t)(n0 + nr) * 2048 + k0 + kch];
    out[0] = tmp.q[0];
    out[1] = tmp.q[1];
}

// ---------- 256x256 8-phase GEMM (T2+T3+T4+T5), K = 2048 ----------
template <bool OUT_BF16>
__device__ __forceinline__ void gemm256_body(
    const ushort* __restrict__ A, const ushort* __restrict__ Bt,
    void* __restrict__ Cout, int ldc, int m0, int n0,
    ushort* As, ushort* Bs) {
    constexpr int K   = 2048;
    constexpr int NKT = K / 64;
    constexpr int VMK = 4;              // in-flight allowance = loads per kh (A2+B2)

    const int tid  = threadIdx.x;
    const int wv   = tid >> 6, lane = tid & 63;
    const int wr   = wv >> 2,  wc   = wv & 3;
    const int mq   = lane & 15, quad = lane >> 4;
    const int cho  = ((quad ^ (mq & 3)) << 3);

    const int srow = tid >> 2;
    const int cxr  = (((tid & 3) ^ (srow & 3)) << 3);
    const ushort* sA0 = A  + (size_t)(m0 + srow) * K + cxr;
    const ushort* sA1 = sA0 + (size_t)128 * K;
    const ushort* sB0 = Bt + (size_t)(n0 + srow) * K + cxr;
    const ushort* sB1 = sB0 + (size_t)128 * K;
    const int sdo = wv * 512;

    const int arow = wr * 128 + mq;
    const int brow = wc * 64 + mq;

    v4f acc[8][4] = {};

    auto stageA = [&](int buf, int kh, int kt) {
        const int ko = kt * 64 + kh * 32;
        ushort* d = As + (buf * 2 + kh) * 8192 + sdo;
        load_lds16(sA0 + ko, d);
        load_lds16(sA1 + ko, d + 4096);
    };
    auto stageB = [&](int buf, int kh, int kt) {
        const int ko = kt * 64 + kh * 32;
        ushort* d = Bs + (buf * 2 + kh) * 8192 + sdo;
        load_lds16(sB0 + ko, d);
        load_lds16(sB1 + ko, d + 4096);
    };
    auto rdA = [&](v8bf (&r)[4], const ushort* kb, int r0) {
#pragma unroll
        for (int i = 0; i < 4; ++i)
            r[i] = *(const v8bf*)&kb[(r0 + i * 16) * 32 + cho];
    };
    auto rdB = [&](v8bf (&r)[4], const ushort* kb) {
#pragma unroll
        for (int i = 0; i < 4; ++i)
            r[i] = *(const v8bf*)&kb[(brow + i * 16) * 32 + cho];
    };
    auto mma = [&](int mtb, const v8bf (&a)[4], const v8bf (&b)[4]) {
#pragma unroll
        for (int i = 0; i < 4; ++i)
#pragma unroll
            for (int nt = 0; nt < 4; ++nt)
                acc[mtb + i][nt] = __builtin_amdgcn_mfma_f32_16x16x32_bf16(
                    a[i], b[nt], acc[mtb + i][nt], 0, 0, 0);
    };

    stageA(0, 0, 0); stageB(0, 0, 0); stageA(0, 1, 0); stageB(0, 1, 0);
    vmwait<VMK>();
    __builtin_amdgcn_s_barrier();
    __builtin_amdgcn_sched_barrier(0);

#pragma unroll 1
    for (int t = 0; t < NKT; ++t) {
        const int p = t & 1, pn = p ^ 1;
        const bool more = (t + 1 < NKT);
        const ushort* a0 = As + p * 16384;
        const ushort* a1 = a0 + 8192;
        const ushort* b0 = Bs + p * 16384;
        const ushort* b1 = b0 + 8192;
        v8bf af[4], bfr[4];

        rdA(af, a0, arow); rdB(bfr, b0);
        if (more) stageA(pn, 0, t + 1);
        pbar();
        __builtin_amdgcn_s_setprio(1); mma(0, af, bfr); __builtin_amdgcn_s_setprio(0);
        pbar();
        rdA(af, a0, arow + 64);
        if (more) stageB(pn, 0, t + 1);
        pbar();
        __builtin_amdgcn_s_setprio(1); mma(4, af, bfr); __builtin_amdgcn_s_setprio(0);
        if (more) vmwait<VMK>(); else vmwait<0>();
        pbar();
        rdA(af, a1, arow); rdB(bfr, b1);
        if (more) stageA(pn, 1, t + 1);
        pbar();
        __builtin_amdgcn_s_setprio(1); mma(0, af, bfr); __builtin_amdgcn_s_setprio(0);
        pbar();
        rdA(af, a1, arow + 64);
        if (more) stageB(pn, 1, t + 1);
        pbar();
        __builtin_amdgcn_s_setprio(1); mma(4, af, bfr); __builtin_amdgcn_s_setprio(0);
        if (more) vmwait<VMK>();
        pbar();
    }

#pragma unroll
    for (int mt = 0; mt < 8; ++mt) {
        const int r = m0 + wr * 128 + mt * 16 + quad * 4;
#pragma unroll
        for (int nt = 0; nt < 4; ++nt) {
            const int c = n0 + wc * 64 + nt * 16 + mq;
#pragma unroll
            for (int reg = 0; reg < 4; ++reg) {
                if (OUT_BF16)
                    ((ushort*)Cout)[(size_t)(r + reg) * ldc + c] = f2bf(acc[mt][nt][reg]);
                else
                    ((float*)Cout)[(size_t)(r + reg) * ldc + c] = acc[mt][nt][reg];
            }
        }
    }
}

// ---------- 128x256 8-phase GEMM (full 256-block grid for gemm_out) ----------
template <bool OUT_BF16>
__device__ __forceinline__ void gemm128_body(
    const ushort* __restrict__ A, const ushort* __restrict__ Bt,
    void* __restrict__ Cout, int ldc, int m0, int n0,
    ushort* As, ushort* Bs) {
    constexpr int K   = 2048;
    constexpr int NKT = K / 64;

    const int tid  = threadIdx.x;
    const int wv   = tid >> 6, lane = tid & 63;
    const int wr   = wv >> 2,  wc   = wv & 3;
    const int mq   = lane & 15, quad = lane >> 4;
    const int cho  = ((quad ^ (mq & 3)) << 3);

    const int srow = tid >> 2;
    const int cxr  = (((tid & 3) ^ (srow & 3)) << 3);
    const ushort* sA0 = A  + (size_t)(m0 + srow) * K + cxr;
    const ushort* sB0 = Bt + (size_t)(n0 + srow) * K + cxr;
    const ushort* sB1 = sB0 + (size_t)128 * K;
    const int sdo = wv * 512;

    const int arow = wr * 64 + mq;
    const int brow = wc * 64 + mq;

    v4f acc[4][4] = {};

    auto stage = [&](int buf, int kh, int kt) {   // A(1) + B(2) loads per kh
        const int ko = kt * 64 + kh * 32;
        load_lds16(sA0 + ko, As + (buf * 2 + kh) * 4096 + sdo);
        ushort* d = Bs + (buf * 2 + kh) * 8192 + sdo;
        load_lds16(sB0 + ko, d);
        load_lds16(sB1 + ko, d + 4096);
    };
    auto rd4 = [&](v8bf (&r)[4], const ushort* kb, int r0) {
#pragma unroll
        for (int i = 0; i < 4; ++i)
            r[i] = *(const v8bf*)&kb[(r0 + i * 16) * 32 + cho];
    };
    auto mma = [&](const v8bf (&a)[4], const v8bf (&b)[4]) {
#pragma unroll
        for (int i = 0; i < 4; ++i)
#pragma unroll
            for (int nt = 0; nt < 4; ++nt)
                acc[i][nt] = __builtin_amdgcn_mfma_f32_16x16x32_bf16(
                    a[i], b[nt], acc[i][nt], 0, 0, 0);
    };

    stage(0, 0, 0); stage(0, 1, 0);
    vmwait<3>();
    __builtin_amdgcn_s_barrier();
    __builtin_amdgcn_sched_barrier(0);

#pragma unroll 1
    for (int t = 0; t < NKT; ++t) {
        const int p = t & 1, pn = p ^ 1;
        const bool more = (t + 1 < NKT);
        const ushort* a0 = As + p * 8192;
        const ushort* a1 = a0 + 4096;
        const ushort* b0 = Bs + p * 16384;
        const ushort* b1 = b0 + 8192;
        v8bf af[4], bfr[4];

        // kh0 phase
        rd4(af, a0, arow); rd4(bfr, b0, brow);
        if (more) stage(pn, 0, t + 1);
        pbar();
        __builtin_amdgcn_s_setprio(1); mma(af, bfr); __builtin_amdgcn_s_setprio(0);
        if (more) vmwait<3>(); else vmwait<0>();
        pbar();
        // kh1 phase
        rd4(af, a1, arow); rd4(bfr, b1, brow);
        if (more) stage(pn, 1, t + 1);
        pbar();
        __builtin_amdgcn_s_setprio(1); mma(af, bfr); __builtin_amdgcn_s_setprio(0);
        if (more) vmwait<3>();
        pbar();
    }

#pragma unroll
    for (int mt = 0; mt < 4; ++mt) {
        const int r = m0 + wr * 64 + mt * 16 + quad * 4;
#pragma unroll
        for (int nt = 0; nt < 4; ++nt) {
            const int c = n0 + wc * 64 + nt * 16 + mq;
#pragma unroll
            for (int reg = 0; reg < 4; ++reg) {
                if (OUT_BF16)
                    ((ushort*)Cout)[(size_t)(r + reg) * ldc + c] = f2bf(acc[mt][nt][reg]);
                else
                    ((float*)Cout)[(size_t)(r + reg) * ldc + c] = acc[mt][nt][reg];
            }
        }
    }
}

// fused QK-projection (160 blocks) + V^T-projection (32 blocks)
__global__ __launch_bounds__(512, 2) void gemm_qkv(
    const ushort* __restrict__ xb, const ushort* __restrict__ wqk_t,
    const ushort* __restrict__ wv_t, ushort* __restrict__ qkb,
    ushort* __restrict__ vtb) {
    __shared__ __align__(16) ushort As[32768];   // 64 KB
    __shared__ __align__(16) ushort Bs[32768];   // 64 KB
    int w = (blockIdx.x & 7) * 24 + (blockIdx.x >> 3);   // XCD-chunked (192 = 8*24)
    const ushort *Ap, *Bp; ushort* Cp; int ldc, m0, n0;
    if (w < 160) {   // qkb[4096][2560] = xb * wqk_t^T
        Ap = xb; Bp = wqk_t; Cp = qkb; ldc = 2560;
        m0 = (w / 10) * 256; n0 = (w % 10) * 256;
    } else {         // vtb[512][4096] = wv_t * xb^T
        w -= 160;
        Ap = wv_t; Bp = xb; Cp = vtb; ldc = 4096;
        m0 = (w >> 4) * 256; n0 = (w & 15) * 256;
    }
    gemm256_body<true>(Ap, Bp, Cp, ldc, m0, n0, As, Bs);
}

// output projection: d_out[4096][2048] f32 = attn_out * wo_t^T
// 128x256 tiles -> 32x8 = 256 blocks = exactly 1/CU, 16 MFMA/phase
__global__ __launch_bounds__(512, 2) void gemm_out(
    const ushort* __restrict__ A, const ushort* __restrict__ Bt,
    float* __restrict__ C) {
    __shared__ __align__(16) ushort As[16384];   // 32 KB
    __shared__ __align__(16) ushort Bs[32768];   // 64 KB
    const int w = (blockIdx.x & 7) * 32 + (blockIdx.x >> 3);   // 256 = 8*32
    gemm128_body<false>(A, Bt, C, 2048, (w >> 3) * 128, (w & 7) * 256, As, Bs);
}

// ---------- flash attention v12 ----------
// v12 = v10's verified inner loop (2 q-groups/wave, 56 VGPR) with EQUAL-WORK
// blocks: grid 512; block (b,h,j) processes q-tile j then q-tile 15-j
// sequentially. Every block = (2j+2)+(2(15-j)+2) = 34 rounds, identical ->
// both co-resident blocks per CU ({i, i+256} = b0/b1, same 34 rounds) live
// the whole kernel: steady 8 waves/CU, no straggler tail.
// (v11's 4-group variant regressed: Occ 13.5%, long block ran solo. Reverted.)
constexpr float SC2 = 0.18033688011f;   // 0.125 * log2(e)
constexpr float MB2 = 14.4269504089f;   // 10 * log2(e)  (fixed softmax max M=10, exact)

template <bool MASK>
__device__ __forceinline__ void attn_compute(
    int kv0, int qrow, int mq, int quad, int lane_lo,
    const ushort* Ks, const ushort* Vs, const v8bf ones,
    const v8bf (&qf)[2][2], v4f (&oacc)[2][4], v4f (&osum)[2]) {
    const bool hi = quad >= 2;
    const int swz = mq & 7;
#pragma unroll
    for (int half = 0; half < 2; ++half) {
        uint32_t pk[2][2][2];
#pragma unroll
        for (int ntl = 0; ntl < 2; ++ntl) {
            const int nt = 2 * half + ntl;
            v4f sacc[2] = {{0.f,0.f,0.f,0.f}, {0.f,0.f,0.f,0.f}};
#pragma unroll
            for (int ks = 0; ks < 2; ++ks) {
                v8bf kb = *(const v8bf*)&Ks[(nt * 16 + mq) * 64 + (((ks << 2) + quad) ^ swz) * 8];
                sacc[0] = __builtin_amdgcn_mfma_f32_16x16x32_bf16(kb, qf[0][ks], sacc[0], 0, 0, 0);
                sacc[1] = __builtin_amdgcn_mfma_f32_16x16x32_bf16(kb, qf[1][ks], sacc[1], 0, 0, 0);
            }
#pragma unroll
            for (int g = 0; g < 2; ++g) {
                float pr[4];
#pragma unroll
                for (int reg = 0; reg < 4; ++reg) {
                    float s = sacc[g][reg];
                    if (MASK) {
                        const int kv = kv0 + nt * 16 + quad * 4 + reg;
                        const int q  = qrow + 16 * g + mq;
                        if (kv > q) s = -3.0e38f;
                    }
                    pr[reg] = __builtin_amdgcn_exp2f(fmaf(s, SC2, -MB2));
                }
                pk[g][ntl][0] = pack2bf(pr[0], pr[1]);
                pk[g][ntl][1] = pack2bf(pr[2], pr[3]);
            }
        }
        v8bf pf[2];
#pragma unroll
        for (int g = 0; g < 2; ++g) {
            uint32_t a0 = __shfl(pk[g][0][0], lane_lo);
            uint32_t b0 = __shfl(pk[g][1][0], lane_lo);
            uint32_t a1 = __shfl(pk[g][0][1], lane_lo);
            uint32_t b1 = __shfl(pk[g][1][1], lane_lo);
            uint32_t a2 = __shfl(pk[g][0][0], lane_lo + 16);
            uint32_t b2 = __shfl(pk[g][1][0], lane_lo + 16);
            uint32_t a3 = __shfl(pk[g][0][1], lane_lo + 16);
            uint32_t b3 = __shfl(pk[g][1][1], lane_lo + 16);
            union { uint32_t d[4]; v8bf v; } u;
            u.d[0] = hi ? b0 : a0;
            u.d[1] = hi ? b1 : a1;
            u.d[2] = hi ? b2 : a2;
            u.d[3] = hi ? b3 : a3;
            pf[g] = u.v;
            osum[g] = __builtin_amdgcn_mfma_f32_16x16x32_bf16(pf[g], ones, osum[g], 0, 0, 0);
        }
#pragma unroll
        for (int hdt = 0; hdt < 4; ++hdt) {
            v8bf vb = *(const v8bf*)&Vs[(hdt * 16 + mq) * 64 + (((half << 2) + quad) ^ swz) * 8];
            oacc[0][hdt] = __builtin_amdgcn_mfma_f32_16x16x32_bf16(pf[0], vb, oacc[0][hdt], 0, 0, 0);
            oacc[1][hdt] = __builtin_amdgcn_mfma_f32_16x16x32_bf16(pf[1], vb, oacc[1][hdt], 0, 0, 0);
        }
    }
}

// qkb: [B*T][2560] bf16 (Q|K); vt: [512][4096] bf16; out: [B*T][2048] bf16
// 256 threads / 4 waves; two sequential 128-row q-tiles per block (j, 15-j).
// LDS 32 KB dbuf; grid 512 = 2 blocks/CU, all blocks 34 rounds.
__global__ __launch_bounds__(256, 4) void attn_fwd(
    const ushort* __restrict__ qkb, const ushort* __restrict__ vt,
    ushort* __restrict__ outp) {
    __shared__ __align__(16) ushort Ks[2][4096];   // [buf][64 rows][64 cols], chunk-swizzled
    __shared__ __align__(16) ushort Vs[2][4096];

    const int tid  = threadIdx.x;
    const int wv   = tid >> 6, lane = tid & 63;
    const int mq = lane & 15, quad = lane >> 4;
    const int lane_lo = (quad & 1) * 32 + mq;

    const int i = blockIdx.x;
    const int u = i & 255;
    const int h = u & 31, j = u >> 5;      // j in [0,8)
    const int b = i >> 8;                  // b in {0,1}
    const int g = h >> 2;

    union { ushort u[8]; v8bf v; } one_u;
#pragma unroll
    for (int ii = 0; ii < 8; ++ii) one_u.u[ii] = 0x3F80;   // bf16 1.0
    const v8bf ones = one_u.v;

    const ushort* kg = qkb + (size_t)(b * 2048) * 2560 + 2048 + g * 64;
    const ushort* vg = vt + (size_t)(g * 64) * 4096 + b * 2048;

    // staging geometry: wave wv covers rows wv*16 .. wv*16+15 (two 8-row groups).
    // LDS dest is LINEAR (global_load_lds: base + lane*16); swizzle applied to
    // the per-lane GLOBAL source chunk so LDS slot (r,c) holds global chunk c^(r&7).
    const int sr = lane >> 3;
    const int gc = (lane & 7) ^ sr;
    const ushort* kb0 = kg + (size_t)(wv * 16 + sr) * 2560 + gc * 8;
    const ushort* kb1 = kb0 + (size_t)8 * 2560;
    const ushort* vb0 = vg + (size_t)(wv * 16 + sr) * 4096 + gc * 8;
    const ushort* vb1 = vb0 + (size_t)8 * 4096;
    const int ldso = wv * 1024;

#pragma unroll 1
    for (int pp = 0; pp < 2; ++pp) {
        const int qt   = pp ? (15 - j) : j;
        const int qrow = qt * 128 + wv * 32;

        v8bf qf[2][2];
#pragma unroll
        for (int gg = 0; gg < 2; ++gg) {
            const ushort* qp = qkb + (size_t)(b * 2048 + qrow + 16 * gg + mq) * 2560 + h * 64 + quad * 8;
            qf[gg][0] = *(const v8bf*)qp;
            qf[gg][1] = *(const v8bf*)(qp + 32);
        }

        v4f oacc[2][4] = {};
        v4f osum[2] = {};

        const int ntiles = 2 * qt + 2;

        // prologue: DMA tile 0 into buffer 0
        load_lds16(kb0, &Ks[0][ldso]);
        load_lds16(kb1, &Ks[0][ldso + 512]);
        load_lds16(vb0, &Vs[0][ldso]);
        load_lds16(vb1, &Vs[0][ldso + 512]);
        __syncthreads();

#pragma unroll 1
        for (int jt = 0; jt < ntiles; ++jt) {
            const int kv0 = jt * 64;
            const int p = jt & 1;
            if (jt + 1 < ntiles) {   // DMA-prefetch next tile into the other buffer
                const int nk = kv0 + 64;
                load_lds16(kb0 + (size_t)nk * 2560, &Ks[p ^ 1][ldso]);
                load_lds16(kb1 + (size_t)nk * 2560, &Ks[p ^ 1][ldso + 512]);
                load_lds16(vb0 + nk, &Vs[p ^ 1][ldso]);
                load_lds16(vb1 + nk, &Vs[p ^ 1][ldso + 512]);
            }
            // kv0 - qrow multiple of 32 -> both groups active iff kv0 <= qrow;
            // masked iff kv0 + 64 > qrow (exactly one such tile per wave).
            if (kv0 <= qrow) {
                if (kv0 + 64 > qrow)
                    attn_compute<true>(kv0, qrow, mq, quad, lane_lo, Ks[p], Vs[p], ones, qf, oacc, osum);
                else
                    attn_compute<false>(kv0, qrow, mq, quad, lane_lo, Ks[p], Vs[p], ones, qf, oacc, osum);
            }
            __syncthreads();   // joins waves; compiler's vmcnt(0) drain completes the DMA
        }

        // normalize: osum is in C-layout identical to oacc — no shuffles
#pragma unroll
        for (int gg = 0; gg < 2; ++gg) {
#pragma unroll
            for (int reg = 0; reg < 4; ++reg) {
                const float invr = 1.0f / osum[gg][reg];
                const int rr = qrow + 16 * gg + quad * 4 + reg;
#pragma unroll
                for (int hdt = 0; hdt < 4; ++hdt)
                    outp[(size_t)(b * 2048 + rr) * 2048 + h * 64 + hdt * 16 + mq] =
                        f2bf(oacc[gg][hdt][reg] * invr);
            }
        }
    }
}

// ---------- launch ----------
extern "C" void kernel_launch(void* const* d_in, const int* in_sizes, int n_in,
                              void* d_out, int out_size, void* d_ws, size_t ws_size,
                              hipStream_t stream) {
    const float* x  = (const float*)d_in[0];
    const float* Wq = (const float*)d_in[1];
    const float* Wk = (const float*)d_in[2];
    const float* Wv = (const float*)d_in[3];
    const float* Wo = (const float*)d_in[4];

    char* ws = (char*)d_ws;
    ushort* xb    = (ushort*)(ws);                  // [4096][2048] x bf16; later attn output
    ushort* wqk_t = (ushort*)(ws + 16777216);       // [2560][2048]
    ushort* wv_t  = (ushort*)(ws + 27262976);       // [512][2048]
    ushort* wo_t  = (ushort*)(ws + 29360128);       // [2048][2048]
    ushort* qkb   = (ushort*)(ws + 37748736);       // [4096][2560]  Q|K
    ushort* vtb   = (ushort*)(ws + 58720256);       // [512][4096]   V^T

    cvt_f32_bf16_k<<<8192, 256, 0, stream>>>((const float4*)x, xb, 2097152);
    transpose_all<<<dim3(80, 32), 256, 0, stream>>>(Wq, Wk, Wv, Wo, wqk_t, wv_t, wo_t);

    gemm_qkv<<<192, 512, 0, stream>>>(xb, wqk_t, wv_t, qkb, vtb);
    attn_fwd<<<512, 256, 0, stream>>>(qkb, vtb, xb);
    gemm_out<<<256, 512, 0, stream>>>(xb, wo_t, (float*)d_out);
}

// Round 8
// 284.624 us; speedup vs baseline: 1.0795x; 1.0226x over previous
//
#include <hip/hip_runtime.h>
#include <hip/hip_bf16.h>
#include <stdint.h>

// ---------- types ----------
typedef __bf16 v8bf __attribute__((ext_vector_type(8)));
typedef float  v4f  __attribute__((ext_vector_type(4)));

__device__ __forceinline__ ushort f2bf(float f) {
    union { float f; uint32_t u; } x; x.f = f;
    uint32_t r = (x.u + 0x7FFFu + ((x.u >> 16) & 1u)) >> 16;
    return (ushort)r;
}
// pack two non-negative floats to bf16x2 (round-half-up): 2 add + 1 v_perm
__device__ __forceinline__ uint32_t pack2bf(float a, float b) {
    union { float f; uint32_t u; } xa, xb; xa.f = a; xb.f = b;
    return __builtin_amdgcn_perm(xb.u + 0x8000u, xa.u + 0x8000u, 0x07060302u);
}

__device__ __forceinline__ void load_lds16(const void* g, void* l) {
    __builtin_amdgcn_global_load_lds(
        (const __attribute__((address_space(1))) uint32_t*)g,
        (__attribute__((address_space(3))) uint32_t*)l, 16, 0, 0);
}

// phase barrier: raw s_barrier (NO implicit vmcnt(0) drain, unlike __syncthreads)
__device__ __forceinline__ void pbar() {
    __builtin_amdgcn_sched_barrier(0);
    __builtin_amdgcn_s_barrier();
    __builtin_amdgcn_sched_barrier(0);
}
template <int N>
__device__ __forceinline__ void vmwait() {
    if constexpr (N == 0)      asm volatile("s_waitcnt vmcnt(0)" ::: "memory");
    else if constexpr (N == 3) asm volatile("s_waitcnt vmcnt(3)" ::: "memory");
    else                       asm volatile("s_waitcnt vmcnt(4)" ::: "memory");
    __builtin_amdgcn_sched_barrier(0);
}

// ---------- merged prep: x f32->bf16 convert + all-weight transpose/convert ----------
// one dispatch instead of two (per-dispatch overhead ~15 us measured as the
// stable gap between sum-of-kernels and total dur).
__global__ __launch_bounds__(256) void prep_all(
    const float4* __restrict__ x4, ushort* __restrict__ xb,
    const float* __restrict__ Wq, const float* __restrict__ Wk,
    const float* __restrict__ Wv, const float* __restrict__ Wo,
    ushort* __restrict__ wqk_t, ushort* __restrict__ wv_t,
    ushort* __restrict__ wo_t) {
    __shared__ ushort tile[64][65];
    const int tid = threadIdx.x;
    const int bid = blockIdx.x;
    if (bid < 8192) {           // ---- cvt part: xb = bf16(x), 2M float4 ----
        const int i = bid * 256 + tid;
        float4 f = x4[i];
        ushort4 u = make_ushort4(f2bf(f.x), f2bf(f.y), f2bf(f.z), f2bf(f.w));
        *(ushort4*)(xb + 4 * (size_t)i) = u;
        return;
    }
    // ---- transpose part (2560 blocks) ----
    const int t  = bid - 8192;
    const int ix = t % 80, k0 = (t / 80) * 64;
    const float* src; ushort* dst; int N, n0;
    if (ix < 32)      { src = Wq; dst = wqk_t;                       N = 2048; n0 = ix * 64; }
    else if (ix < 40) { src = Wk; dst = wqk_t + (size_t)2048 * 2048; N = 512;  n0 = (ix - 32) * 64; }
    else if (ix < 48) { src = Wv; dst = wv_t;                        N = 512;  n0 = (ix - 40) * 64; }
    else              { src = Wo; dst = wo_t;                        N = 2048; n0 = (ix - 48) * 64; }
    const int nn = tid & 63, kb = tid >> 6;
#pragma unroll
    for (int p = 0; p < 16; ++p) {
        int kk = p * 4 + kb;
        tile[kk][nn] = f2bf(src[(size_t)(k0 + kk) * N + n0 + nn]);
    }
    __syncthreads();
    const int nr = tid >> 2, kch = (tid & 3) * 16;
    union { ushort u[16]; uint4 q[2]; } tmp;
#pragma unroll
    for (int j = 0; j < 16; ++j) tmp.u[j] = tile[kch + j][nr];
    uint4* out = (uint4*)&dst[(size_t)(n0 + nr) * 2048 + k0 + kch];
    out[0] = tmp.q[0];
    out[1] = tmp.q[1];
}

// ---------- 256x256 8-phase GEMM (T2+T3+T4+T5), K = 2048 ----------
template <bool OUT_BF16>
__device__ __forceinline__ void gemm256_body(
    const ushort* __restrict__ A, const ushort* __restrict__ Bt,
    void* __restrict__ Cout, int ldc, int m0, int n0,
    ushort* As, ushort* Bs) {
    constexpr int K   = 2048;
    constexpr int NKT = K / 64;
    constexpr int VMK = 4;              // in-flight allowance = loads per kh (A2+B2)

    const int tid  = threadIdx.x;
    const int wv   = tid >> 6, lane = tid & 63;
    const int wr   = wv >> 2,  wc   = wv & 3;
    const int mq   = lane & 15, quad = lane >> 4;
    const int cho  = ((quad ^ (mq & 3)) << 3);

    const int srow = tid >> 2;
    const int cxr  = (((tid & 3) ^ (srow & 3)) << 3);
    const ushort* sA0 = A  + (size_t)(m0 + srow) * K + cxr;
    const ushort* sA1 = sA0 + (size_t)128 * K;
    const ushort* sB0 = Bt + (size_t)(n0 + srow) * K + cxr;
    const ushort* sB1 = sB0 + (size_t)128 * K;
    const int sdo = wv * 512;

    const int arow = wr * 128 + mq;
    const int brow = wc * 64 + mq;

    v4f acc[8][4] = {};

    auto stageA = [&](int buf, int kh, int kt) {
        const int ko = kt * 64 + kh * 32;
        ushort* d = As + (buf * 2 + kh) * 8192 + sdo;
        load_lds16(sA0 + ko, d);
        load_lds16(sA1 + ko, d + 4096);
    };
    auto stageB = [&](int buf, int kh, int kt) {
        const int ko = kt * 64 + kh * 32;
        ushort* d = Bs + (buf * 2 + kh) * 8192 + sdo;
        load_lds16(sB0 + ko, d);
        load_lds16(sB1 + ko, d + 4096);
    };
    auto rdA = [&](v8bf (&r)[4], const ushort* kb, int r0) {
#pragma unroll
        for (int i = 0; i < 4; ++i)
            r[i] = *(const v8bf*)&kb[(r0 + i * 16) * 32 + cho];
    };
    auto rdB = [&](v8bf (&r)[4], const ushort* kb) {
#pragma unroll
        for (int i = 0; i < 4; ++i)
            r[i] = *(const v8bf*)&kb[(brow + i * 16) * 32 + cho];
    };
    auto mma = [&](int mtb, const v8bf (&a)[4], const v8bf (&b)[4]) {
#pragma unroll
        for (int i = 0; i < 4; ++i)
#pragma unroll
            for (int nt = 0; nt < 4; ++nt)
                acc[mtb + i][nt] = __builtin_amdgcn_mfma_f32_16x16x32_bf16(
                    a[i], b[nt], acc[mtb + i][nt], 0, 0, 0);
    };

    stageA(0, 0, 0); stageB(0, 0, 0); stageA(0, 1, 0); stageB(0, 1, 0);
    vmwait<VMK>();
    __builtin_amdgcn_s_barrier();
    __builtin_amdgcn_sched_barrier(0);

#pragma unroll 1
    for (int t = 0; t < NKT; ++t) {
        const int p = t & 1, pn = p ^ 1;
        const bool more = (t + 1 < NKT);
        const ushort* a0 = As + p * 16384;
        const ushort* a1 = a0 + 8192;
        const ushort* b0 = Bs + p * 16384;
        const ushort* b1 = b0 + 8192;
        v8bf af[4], bfr[4];

        rdA(af, a0, arow); rdB(bfr, b0);
        if (more) stageA(pn, 0, t + 1);
        pbar();
        __builtin_amdgcn_s_setprio(1); mma(0, af, bfr); __builtin_amdgcn_s_setprio(0);
        pbar();
        rdA(af, a0, arow + 64);
        if (more) stageB(pn, 0, t + 1);
        pbar();
        __builtin_amdgcn_s_setprio(1); mma(4, af, bfr); __builtin_amdgcn_s_setprio(0);
        if (more) vmwait<VMK>(); else vmwait<0>();
        pbar();
        rdA(af, a1, arow); rdB(bfr, b1);
        if (more) stageA(pn, 1, t + 1);
        pbar();
        __builtin_amdgcn_s_setprio(1); mma(0, af, bfr); __builtin_amdgcn_s_setprio(0);
        pbar();
        rdA(af, a1, arow + 64);
        if (more) stageB(pn, 1, t + 1);
        pbar();
        __builtin_amdgcn_s_setprio(1); mma(4, af, bfr); __builtin_amdgcn_s_setprio(0);
        if (more) vmwait<VMK>();
        pbar();
    }

#pragma unroll
    for (int mt = 0; mt < 8; ++mt) {
        const int r = m0 + wr * 128 + mt * 16 + quad * 4;
#pragma unroll
        for (int nt = 0; nt < 4; ++nt) {
            const int c = n0 + wc * 64 + nt * 16 + mq;
#pragma unroll
            for (int reg = 0; reg < 4; ++reg) {
                if (OUT_BF16)
                    ((ushort*)Cout)[(size_t)(r + reg) * ldc + c] = f2bf(acc[mt][nt][reg]);
                else
                    ((float*)Cout)[(size_t)(r + reg) * ldc + c] = acc[mt][nt][reg];
            }
        }
    }
}

// ---------- 128x256 8-phase GEMM (full 256-block grid for gemm_out) ----------
template <bool OUT_BF16>
__device__ __forceinline__ void gemm128_body(
    const ushort* __restrict__ A, const ushort* __restrict__ Bt,
    void* __restrict__ Cout, int ldc, int m0, int n0,
    ushort* As, ushort* Bs) {
    constexpr int K   = 2048;
    constexpr int NKT = K / 64;

    const int tid  = threadIdx.x;
    const int wv   = tid >> 6, lane = tid & 63;
    const int wr   = wv >> 2,  wc   = wv & 3;
    const int mq   = lane & 15, quad = lane >> 4;
    const int cho  = ((quad ^ (mq & 3)) << 3);

    const int srow = tid >> 2;
    const int cxr  = (((tid & 3) ^ (srow & 3)) << 3);
    const ushort* sA0 = A  + (size_t)(m0 + srow) * K + cxr;
    const ushort* sB0 = Bt + (size_t)(n0 + srow) * K + cxr;
    const ushort* sB1 = sB0 + (size_t)128 * K;
    const int sdo = wv * 512;

    const int arow = wr * 64 + mq;
    const int brow = wc * 64 + mq;

    v4f acc[4][4] = {};

    auto stage = [&](int buf, int kh, int kt) {   // A(1) + B(2) loads per kh
        const int ko = kt * 64 + kh * 32;
        load_lds16(sA0 + ko, As + (buf * 2 + kh) * 4096 + sdo);
        ushort* d = Bs + (buf * 2 + kh) * 8192 + sdo;
        load_lds16(sB0 + ko, d);
        load_lds16(sB1 + ko, d + 4096);
    };
    auto rd4 = [&](v8bf (&r)[4], const ushort* kb, int r0) {
#pragma unroll
        for (int i = 0; i < 4; ++i)
            r[i] = *(const v8bf*)&kb[(r0 + i * 16) * 32 + cho];
    };
    auto mma = [&](const v8bf (&a)[4], const v8bf (&b)[4]) {
#pragma unroll
        for (int i = 0; i < 4; ++i)
#pragma unroll
            for (int nt = 0; nt < 4; ++nt)
                acc[i][nt] = __builtin_amdgcn_mfma_f32_16x16x32_bf16(
                    a[i], b[nt], acc[i][nt], 0, 0, 0);
    };

    stage(0, 0, 0); stage(0, 1, 0);
    vmwait<3>();
    __builtin_amdgcn_s_barrier();
    __builtin_amdgcn_sched_barrier(0);

#pragma unroll 1
    for (int t = 0; t < NKT; ++t) {
        const int p = t & 1, pn = p ^ 1;
        const bool more = (t + 1 < NKT);
        const ushort* a0 = As + p * 8192;
        const ushort* a1 = a0 + 4096;
        const ushort* b0 = Bs + p * 16384;
        const ushort* b1 = b0 + 8192;
        v8bf af[4], bfr[4];

        // kh0 phase
        rd4(af, a0, arow); rd4(bfr, b0, brow);
        if (more) stage(pn, 0, t + 1);
        pbar();
        __builtin_amdgcn_s_setprio(1); mma(af, bfr); __builtin_amdgcn_s_setprio(0);
        if (more) vmwait<3>(); else vmwait<0>();
        pbar();
        // kh1 phase
        rd4(af, a1, arow); rd4(bfr, b1, brow);
        if (more) stage(pn, 1, t + 1);
        pbar();
        __builtin_amdgcn_s_setprio(1); mma(af, bfr); __builtin_amdgcn_s_setprio(0);
        if (more) vmwait<3>();
        pbar();
    }

#pragma unroll
    for (int mt = 0; mt < 4; ++mt) {
        const int r = m0 + wr * 64 + mt * 16 + quad * 4;
#pragma unroll
        for (int nt = 0; nt < 4; ++nt) {
            const int c = n0 + wc * 64 + nt * 16 + mq;
#pragma unroll
            for (int reg = 0; reg < 4; ++reg) {
                if (OUT_BF16)
                    ((ushort*)Cout)[(size_t)(r + reg) * ldc + c] = f2bf(acc[mt][nt][reg]);
                else
                    ((float*)Cout)[(size_t)(r + reg) * ldc + c] = acc[mt][nt][reg];
            }
        }
    }
}

// fused QK-projection (160 blocks) + V^T-projection (32 blocks)
__global__ __launch_bounds__(512, 2) void gemm_qkv(
    const ushort* __restrict__ xb, const ushort* __restrict__ wqk_t,
    const ushort* __restrict__ wv_t, ushort* __restrict__ qkb,
    ushort* __restrict__ vtb) {
    __shared__ __align__(16) ushort As[32768];   // 64 KB
    __shared__ __align__(16) ushort Bs[32768];   // 64 KB
    int w = (blockIdx.x & 7) * 24 + (blockIdx.x >> 3);   // XCD-chunked (192 = 8*24)
    const ushort *Ap, *Bp; ushort* Cp; int ldc, m0, n0;
    if (w < 160) {   // qkb[4096][2560] = xb * wqk_t^T
        Ap = xb; Bp = wqk_t; Cp = qkb; ldc = 2560;
        m0 = (w / 10) * 256; n0 = (w % 10) * 256;
    } else {         // vtb[512][4096] = wv_t * xb^T
        w -= 160;
        Ap = wv_t; Bp = xb; Cp = vtb; ldc = 4096;
        m0 = (w >> 4) * 256; n0 = (w & 15) * 256;
    }
    gemm256_body<true>(Ap, Bp, Cp, ldc, m0, n0, As, Bs);
}

// output projection: d_out[4096][2048] f32 = attn_out * wo_t^T
// 128x256 tiles -> 32x8 = 256 blocks = exactly 1/CU, 16 MFMA/phase
__global__ __launch_bounds__(512, 2) void gemm_out(
    const ushort* __restrict__ A, const ushort* __restrict__ Bt,
    float* __restrict__ C) {
    __shared__ __align__(16) ushort As[16384];   // 32 KB
    __shared__ __align__(16) ushort Bs[32768];   // 64 KB
    const int w = (blockIdx.x & 7) * 32 + (blockIdx.x >> 3);   // 256 = 8*32
    gemm128_body<false>(A, Bt, C, 2048, (w >> 3) * 128, (w & 7) * 256, As, Bs);
}

// ---------- flash attention v13 = v10 (best measured) + T5 setprio ----------
// v10: 2 q-groups/wave, 1024 blocks = 4/CU, per-CU qt sets {2j,2j+1,15-2j,14-2j}
// -> constant 68 rounds/CU. v12's 2-blocks/CU equal-lifetime variant regressed
// (Occ 19.3%, fewer independent blocks to hide the serial chain). setprio(1)
// wraps MFMA clusters only — 4 independent blocks/CU at different phases is
// the regime where attn setprio measured +4-7% (m191).
constexpr float SC2 = 0.18033688011f;   // 0.125 * log2(e)
constexpr float MB2 = 14.4269504089f;   // 10 * log2(e)  (fixed softmax max M=10, exact)

template <bool MASK>
__device__ __forceinline__ void attn_compute(
    int kv0, int qrow, int mq, int quad, int lane_lo,
    const ushort* Ks, const ushort* Vs, const v8bf ones,
    const v8bf (&qf)[2][2], v4f (&oacc)[2][4], v4f (&osum)[2]) {
    const bool hi = quad >= 2;
    const int swz = mq & 7;
#pragma unroll
    for (int half = 0; half < 2; ++half) {
        uint32_t pk[2][2][2];
#pragma unroll
        for (int ntl = 0; ntl < 2; ++ntl) {
            const int nt = 2 * half + ntl;
            v4f sacc[2] = {{0.f,0.f,0.f,0.f}, {0.f,0.f,0.f,0.f}};
            __builtin_amdgcn_s_setprio(1);
#pragma unroll
            for (int ks = 0; ks < 2; ++ks) {
                v8bf kb = *(const v8bf*)&Ks[(nt * 16 + mq) * 64 + (((ks << 2) + quad) ^ swz) * 8];
                sacc[0] = __builtin_amdgcn_mfma_f32_16x16x32_bf16(kb, qf[0][ks], sacc[0], 0, 0, 0);
                sacc[1] = __builtin_amdgcn_mfma_f32_16x16x32_bf16(kb, qf[1][ks], sacc[1], 0, 0, 0);
            }
            __builtin_amdgcn_s_setprio(0);
#pragma unroll
            for (int g = 0; g < 2; ++g) {
                float pr[4];
#pragma unroll
                for (int reg = 0; reg < 4; ++reg) {
                    float s = sacc[g][reg];
                    if (MASK) {
                        const int kv = kv0 + nt * 16 + quad * 4 + reg;
                        const int q  = qrow + 16 * g + mq;
                        if (kv > q) s = -3.0e38f;
                    }
                    pr[reg] = __builtin_amdgcn_exp2f(fmaf(s, SC2, -MB2));
                }
                pk[g][ntl][0] = pack2bf(pr[0], pr[1]);
                pk[g][ntl][1] = pack2bf(pr[2], pr[3]);
            }
        }
        v8bf pf[2];
#pragma unroll
        for (int g = 0; g < 2; ++g) {
            uint32_t a0 = __shfl(pk[g][0][0], lane_lo);
            uint32_t b0 = __shfl(pk[g][1][0], lane_lo);
            uint32_t a1 = __shfl(pk[g][0][1], lane_lo);
            uint32_t b1 = __shfl(pk[g][1][1], lane_lo);
            uint32_t a2 = __shfl(pk[g][0][0], lane_lo + 16);
            uint32_t b2 = __shfl(pk[g][1][0], lane_lo + 16);
            uint32_t a3 = __shfl(pk[g][0][1], lane_lo + 16);
            uint32_t b3 = __shfl(pk[g][1][1], lane_lo + 16);
            union { uint32_t d[4]; v8bf v; } u;
            u.d[0] = hi ? b0 : a0;
            u.d[1] = hi ? b1 : a1;
            u.d[2] = hi ? b2 : a2;
            u.d[3] = hi ? b3 : a3;
            pf[g] = u.v;
            osum[g] = __builtin_amdgcn_mfma_f32_16x16x32_bf16(pf[g], ones, osum[g], 0, 0, 0);
        }
        __builtin_amdgcn_s_setprio(1);
#pragma unroll
        for (int hdt = 0; hdt < 4; ++hdt) {
            v8bf vb = *(const v8bf*)&Vs[(hdt * 16 + mq) * 64 + (((half << 2) + quad) ^ swz) * 8];
            oacc[0][hdt] = __builtin_amdgcn_mfma_f32_16x16x32_bf16(pf[0], vb, oacc[0][hdt], 0, 0, 0);
            oacc[1][hdt] = __builtin_amdgcn_mfma_f32_16x16x32_bf16(pf[1], vb, oacc[1][hdt], 0, 0, 0);
        }
        __builtin_amdgcn_s_setprio(0);
    }
}

// qkb: [B*T][2560] bf16 (Q|K); vt: [512][4096] bf16; out: [B*T][2048] bf16
// 256 threads / 4 waves / 128-row q-tiles (32 rows = 2 groups per wave).
// LDS 32 KB dbuf -> 4 blocks/CU (grid = 1024 = 4/CU).
__global__ __launch_bounds__(256, 4) void attn_fwd(
    const ushort* __restrict__ qkb, const ushort* __restrict__ vt,
    ushort* __restrict__ outp) {
    __shared__ __align__(16) ushort Ks[2][4096];   // [buf][64 rows][64 cols], chunk-swizzled
    __shared__ __align__(16) ushort Vs[2][4096];

    const int tid  = threadIdx.x;
    const int wv   = tid >> 6, lane = tid & 63;
    const int mq = lane & 15, quad = lane >> 4;
    const int lane_lo = (quad & 1) * 32 + mq;

    // balanced work assignment: same-CU blocks {i, i+256, i+512, i+768} get
    // qt sets {2j, 2j+1, 15-2j, 14-2j} -> per-CU tile total = 68, constant.
    const int i = blockIdx.x;
    const int u = i & 255, s = i >> 8;
    const int h = u & 31, j = u >> 5;
    const int b = s >> 1;
    const int qt = (s == 0) ? 2 * j
                 : (s == 1) ? 2 * j + 1
                 : (s == 2) ? 15 - 2 * j
                            : 14 - 2 * j;
    const int g = h >> 2;
    const int qb0  = qt * 128;
    const int qrow = qb0 + wv * 32;

    union { ushort u[8]; v8bf v; } one_u;
#pragma unroll
    for (int ii = 0; ii < 8; ++ii) one_u.u[ii] = 0x3F80;
    const v8bf ones = one_u.v;

    v8bf qf[2][2];
#pragma unroll
    for (int gg = 0; gg < 2; ++gg) {
        const ushort* qp = qkb + (size_t)(b * 2048 + qrow + 16 * gg + mq) * 2560 + h * 64 + quad * 8;
        qf[gg][0] = *(const v8bf*)qp;
        qf[gg][1] = *(const v8bf*)(qp + 32);
    }

    v4f oacc[2][4] = {};
    v4f osum[2] = {};

    const ushort* kg = qkb + (size_t)(b * 2048) * 2560 + 2048 + g * 64;
    const ushort* vg = vt + (size_t)(g * 64) * 4096 + b * 2048;

    // staging: LDS dest linear (global_load_lds), swizzle on per-lane GLOBAL chunk
    const int sr = lane >> 3;
    const int gc = (lane & 7) ^ sr;
    const ushort* kb0 = kg + (size_t)(wv * 16 + sr) * 2560 + gc * 8;
    const ushort* kb1 = kb0 + (size_t)8 * 2560;
    const ushort* vb0 = vg + (size_t)(wv * 16 + sr) * 4096 + gc * 8;
    const ushort* vb1 = vb0 + (size_t)8 * 4096;
    const int ldso = wv * 1024;

    const int ntiles = 2 * qt + 2;

    load_lds16(kb0, &Ks[0][ldso]);
    load_lds16(kb1, &Ks[0][ldso + 512]);
    load_lds16(vb0, &Vs[0][ldso]);
    load_lds16(vb1, &Vs[0][ldso + 512]);
    __syncthreads();

#pragma unroll 1
    for (int jt = 0; jt < ntiles; ++jt) {
        const int kv0 = jt * 64;
        const int p = jt & 1;
        if (jt + 1 < ntiles) {   // DMA-prefetch next tile into the other buffer
            const int nk = kv0 + 64;
            load_lds16(kb0 + (size_t)nk * 2560, &Ks[p ^ 1][ldso]);
            load_lds16(kb1 + (size_t)nk * 2560, &Ks[p ^ 1][ldso + 512]);
            load_lds16(vb0 + nk, &Vs[p ^ 1][ldso]);
            load_lds16(vb1 + nk, &Vs[p ^ 1][ldso + 512]);
        }
        // kv0 - qrow multiple of 32 -> both groups active iff kv0 <= qrow;
        // masked iff kv0 + 64 > qrow (exactly one such tile per wave).
        if (kv0 <= qrow) {
            if (kv0 + 64 > qrow)
                attn_compute<true>(kv0, qrow, mq, quad, lane_lo, Ks[p], Vs[p], ones, qf, oacc, osum);
            else
                attn_compute<false>(kv0, qrow, mq, quad, lane_lo, Ks[p], Vs[p], ones, qf, oacc, osum);
        }
        __syncthreads();   // joins waves; compiler's vmcnt(0) drain completes the DMA
    }

    // normalize: osum is in C-layout identical to oacc — no shuffles
#pragma unroll
    for (int gg = 0; gg < 2; ++gg) {
#pragma unroll
        for (int reg = 0; reg < 4; ++reg) {
            const float invr = 1.0f / osum[gg][reg];
            const int rr = qrow + 16 * gg + quad * 4 + reg;
#pragma unroll
            for (int hdt = 0; hdt < 4; ++hdt)
                outp[(size_t)(b * 2048 + rr) * 2048 + h * 64 + hdt * 16 + mq] =
                    f2bf(oacc[gg][hdt][reg] * invr);
        }
    }
}

// ---------- launch ----------
extern "C" void kernel_launch(void* const* d_in, const int* in_sizes, int n_in,
                              void* d_out, int out_size, void* d_ws, size_t ws_size,
                              hipStream_t stream) {
    const float* x  = (const float*)d_in[0];
    const float* Wq = (const float*)d_in[1];
    const float* Wk = (const float*)d_in[2];
    const float* Wv = (const float*)d_in[3];
    const float* Wo = (const float*)d_in[4];

    char* ws = (char*)d_ws;
    ushort* xb    = (ushort*)(ws);                  // [4096][2048] x bf16; later attn output
    ushort* wqk_t = (ushort*)(ws + 16777216);       // [2560][2048]
    ushort* wv_t  = (ushort*)(ws + 27262976);       // [512][2048]
    ushort* wo_t  = (ushort*)(ws + 29360128);       // [2048][2048]
    ushort* qkb   = (ushort*)(ws + 37748736);       // [4096][2560]  Q|K
    ushort* vtb   = (ushort*)(ws + 58720256);       // [512][4096]   V^T

    prep_all<<<10752, 256, 0, stream>>>((const float4*)x, xb, Wq, Wk, Wv, Wo,
                                        wqk_t, wv_t, wo_t);
    gemm_qkv<<<192, 512, 0, stream>>>(xb, wqk_t, wv_t, qkb, vtb);
    attn_fwd<<<1024, 256, 0, stream>>>(qkb, vtb, xb);
    gemm_out<<<256, 512, 0, stream>>>(xb, wo_t, (float*)d_out);
}

// Round 9
// 278.476 us; speedup vs baseline: 1.1034x; 1.0221x over previous
//
#include <hip/hip_runtime.h>
#include <hip/hip_bf16.h>
#include <stdint.h>

// ---------- types ----------
typedef __bf16 v8bf __attribute__((ext_vector_type(8)));
typedef float  v4f  __attribute__((ext_vector_type(4)));

__device__ __forceinline__ ushort f2bf(float f) {
    union { float f; uint32_t u; } x; x.f = f;
    uint32_t r = (x.u + 0x7FFFu + ((x.u >> 16) & 1u)) >> 16;
    return (ushort)r;
}
// pack two non-negative floats to bf16x2 (round-half-up): 2 add + 1 v_perm
__device__ __forceinline__ uint32_t pack2bf(float a, float b) {
    union { float f; uint32_t u; } xa, xb; xa.f = a; xb.f = b;
    return __builtin_amdgcn_perm(xb.u + 0x8000u, xa.u + 0x8000u, 0x07060302u);
}

__device__ __forceinline__ void load_lds16(const void* g, void* l) {
    __builtin_amdgcn_global_load_lds(
        (const __attribute__((address_space(1))) uint32_t*)g,
        (__attribute__((address_space(3))) uint32_t*)l, 16, 0, 0);
}

// phase barrier: raw s_barrier (NO implicit vmcnt(0) drain, unlike __syncthreads)
__device__ __forceinline__ void pbar() {
    __builtin_amdgcn_sched_barrier(0);
    __builtin_amdgcn_s_barrier();
    __builtin_amdgcn_sched_barrier(0);
}
template <int N>
__device__ __forceinline__ void vmwait() {
    if constexpr (N == 0)      asm volatile("s_waitcnt vmcnt(0)" ::: "memory");
    else if constexpr (N == 3) asm volatile("s_waitcnt vmcnt(3)" ::: "memory");
    else                       asm volatile("s_waitcnt vmcnt(4)" ::: "memory");
    __builtin_amdgcn_sched_barrier(0);
}

// ---------- merged prep: x f32->bf16 convert + all-weight transpose/convert ----------
__global__ __launch_bounds__(256) void prep_all(
    const float4* __restrict__ x4, ushort* __restrict__ xb,
    const float* __restrict__ Wq, const float* __restrict__ Wk,
    const float* __restrict__ Wv, const float* __restrict__ Wo,
    ushort* __restrict__ wqk_t, ushort* __restrict__ wv_t,
    ushort* __restrict__ wo_t) {
    __shared__ ushort tile[64][65];
    const int tid = threadIdx.x;
    const int bid = blockIdx.x;
    if (bid < 8192) {           // ---- cvt part: xb = bf16(x), 2M float4 ----
        const int i = bid * 256 + tid;
        float4 f = x4[i];
        ushort4 u = make_ushort4(f2bf(f.x), f2bf(f.y), f2bf(f.z), f2bf(f.w));
        *(ushort4*)(xb + 4 * (size_t)i) = u;
        return;
    }
    // ---- transpose part (2560 blocks) ----
    const int t  = bid - 8192;
    const int ix = t % 80, k0 = (t / 80) * 64;
    const float* src; ushort* dst; int N, n0;
    if (ix < 32)      { src = Wq; dst = wqk_t;                       N = 2048; n0 = ix * 64; }
    else if (ix < 40) { src = Wk; dst = wqk_t + (size_t)2048 * 2048; N = 512;  n0 = (ix - 32) * 64; }
    else if (ix < 48) { src = Wv; dst = wv_t;                        N = 512;  n0 = (ix - 40) * 64; }
    else              { src = Wo; dst = wo_t;                        N = 2048; n0 = (ix - 48) * 64; }
    const int nn = tid & 63, kb = tid >> 6;
#pragma unroll
    for (int p = 0; p < 16; ++p) {
        int kk = p * 4 + kb;
        tile[kk][nn] = f2bf(src[(size_t)(k0 + kk) * N + n0 + nn]);
    }
    __syncthreads();
    const int nr = tid >> 2, kch = (tid & 3) * 16;
    union { ushort u[16]; uint4 q[2]; } tmp;
#pragma unroll
    for (int j = 0; j < 16; ++j) tmp.u[j] = tile[kch + j][nr];
    uint4* out = (uint4*)&dst[(size_t)(n0 + nr) * 2048 + k0 + kch];
    out[0] = tmp.q[0];
    out[1] = tmp.q[1];
}

// ---------- fused QKV projection: 256x192-tile 8-phase GEMM, FULL 256-block fill ----------
// C[4096][3072] = xb @ wqkv_t^T where wqkv_t = [Wq^T|Wk^T|Wv^T] rows (contiguous in ws).
// Tiles 256x192 -> 16x16 = 256 blocks = exactly 1/CU (was 192/256 CUs at 256x256).
// Cols < 2560 -> qkb[m][c]; cols >= 2560 (V) -> scatter-transposed to vtb[c-2560][m]
// so attn's V^T layout is preserved with zero attn changes.
// B-staging per K-half = 12KB: 8KB all-wave DMA + 4KB waves 0-3; per-wave counted
// vmcnt = 4 (waves 0-3) / 3 (waves 4-7) — each wave drains its OWN slice to the
// same logical depth before the shared barrier, so all consumers are safe.
__global__ __launch_bounds__(512, 2) void gemm_qkv(
    const ushort* __restrict__ xb, const ushort* __restrict__ wqkv_t,
    ushort* __restrict__ qkb, ushort* __restrict__ vtb) {
    __shared__ __align__(16) ushort As[32768];   // 64 KB: 2buf x 2kh x [256][32]
    __shared__ __align__(16) ushort Bs[24576];   // 48 KB: 2buf x 2kh x [192][32]
    constexpr int K = 2048, NKT = 32;

    const int w  = (blockIdx.x & 7) * 32 + (blockIdx.x >> 3);   // XCD-chunked
    const int m0 = (w >> 4) * 256, n0 = (w & 15) * 192;

    const int tid  = threadIdx.x;
    const int wv   = tid >> 6, lane = tid & 63;
    const int wr   = wv >> 2,  wc   = wv & 3;
    const int mq   = lane & 15, quad = lane >> 4;
    const int cho  = ((quad ^ (mq & 3)) << 3);

    const int srow = tid >> 2;
    const int cxr  = (((tid & 3) ^ (srow & 3)) << 3);
    const ushort* sA0 = xb + (size_t)(m0 + srow) * K + cxr;
    const ushort* sA1 = sA0 + (size_t)128 * K;
    const ushort* sB1p = wqkv_t + (size_t)(n0 + srow) * K + cxr;
    const int srB2 = 128 + srow;        // rows 128-191, staged by waves 0-3
    const ushort* sB2p = wqkv_t + (size_t)(n0 + srB2) * K + (((tid & 3) ^ (srB2 & 3)) << 3);
    const int sdo = wv * 512;

    const int arow = wr * 128 + mq;
    const int brow = wc * 48 + mq;

    v4f acc[8][3] = {};

    auto stageA = [&](int buf, int kh, int kt) {
        const int ko = kt * 64 + kh * 32;
        ushort* d = As + (buf * 2 + kh) * 8192 + sdo;
        load_lds16(sA0 + ko, d);
        load_lds16(sA1 + ko, d + 4096);
    };
    auto stageB = [&](int buf, int kh, int kt) {
        const int ko = kt * 64 + kh * 32;
        ushort* d = Bs + (buf * 2 + kh) * 6144 + sdo;
        load_lds16(sB1p + ko, d);                       // rows 0-127 (8 KB, all waves)
        if (wv < 4) load_lds16(sB2p + ko, d + 4096);    // rows 128-191 (4 KB, waves 0-3)
    };
    auto rdA = [&](v8bf (&r)[4], const ushort* kb, int r0) {
#pragma unroll
        for (int i = 0; i < 4; ++i)
            r[i] = *(const v8bf*)&kb[(r0 + i * 16) * 32 + cho];
    };
    auto rdB = [&](v8bf (&r)[3], const ushort* kb) {
#pragma unroll
        for (int i = 0; i < 3; ++i)
            r[i] = *(const v8bf*)&kb[(brow + i * 16) * 32 + cho];
    };
    auto mma = [&](int mtb, const v8bf (&a)[4], const v8bf (&b)[3]) {
#pragma unroll
        for (int i = 0; i < 4; ++i)
#pragma unroll
            for (int nt = 0; nt < 3; ++nt)
                acc[mtb + i][nt] = __builtin_amdgcn_mfma_f32_16x16x32_bf16(
                    a[i], b[nt], acc[mtb + i][nt], 0, 0, 0);
    };
    auto vmw = [&]() { if (wv < 4) vmwait<4>(); else vmwait<3>(); };

    stageA(0, 0, 0); stageB(0, 0, 0); stageA(0, 1, 0); stageB(0, 1, 0);
    vmw();
    __builtin_amdgcn_s_barrier();
    __builtin_amdgcn_sched_barrier(0);

#pragma unroll 1
    for (int t = 0; t < NKT; ++t) {
        const int p = t & 1, pn = p ^ 1;
        const bool more = (t + 1 < NKT);
        const ushort* a0 = As + p * 16384;
        const ushort* a1 = a0 + 8192;
        const ushort* b0 = Bs + p * 12288;
        const ushort* b1 = b0 + 6144;
        v8bf af[4], bfr[3];

        rdA(af, a0, arow); rdB(bfr, b0);
        if (more) stageA(pn, 0, t + 1);
        pbar();
        __builtin_amdgcn_s_setprio(1); mma(0, af, bfr); __builtin_amdgcn_s_setprio(0);
        pbar();
        rdA(af, a0, arow + 64);
        if (more) stageB(pn, 0, t + 1);
        pbar();
        __builtin_amdgcn_s_setprio(1); mma(4, af, bfr); __builtin_amdgcn_s_setprio(0);
        if (more) vmw(); else vmwait<0>();
        pbar();
        rdA(af, a1, arow); rdB(bfr, b1);
        if (more) stageA(pn, 1, t + 1);
        pbar();
        __builtin_amdgcn_s_setprio(1); mma(0, af, bfr); __builtin_amdgcn_s_setprio(0);
        pbar();
        rdA(af, a1, arow + 64);
        if (more) stageB(pn, 1, t + 1);
        pbar();
        __builtin_amdgcn_s_setprio(1); mma(4, af, bfr); __builtin_amdgcn_s_setprio(0);
        if (more) vmw();
        pbar();
    }

    // epilogue: frag boundary 2560 is a multiple of 16 -> per-frag uniform branch
#pragma unroll
    for (int mt = 0; mt < 8; ++mt) {
        const int r = m0 + wr * 128 + mt * 16 + quad * 4;
#pragma unroll
        for (int nt = 0; nt < 3; ++nt) {
            const int c = n0 + wc * 48 + nt * 16 + mq;
            if (c < 2560) {
#pragma unroll
                for (int reg = 0; reg < 4; ++reg)
                    qkb[(size_t)(r + reg) * 2560 + c] = f2bf(acc[mt][nt][reg]);
            } else {   // V: transposed scatter -> vtb[hd][b*2048+t] (attn's V^T layout)
#pragma unroll
                for (int reg = 0; reg < 4; ++reg)
                    vtb[(size_t)(c - 2560) * 4096 + (r + reg)] = f2bf(acc[mt][nt][reg]);
            }
        }
    }
}

// ---------- 128x256 8-phase GEMM (full 256-block grid for gemm_out) ----------
template <bool OUT_BF16>
__device__ __forceinline__ void gemm128_body(
    const ushort* __restrict__ A, const ushort* __restrict__ Bt,
    void* __restrict__ Cout, int ldc, int m0, int n0,
    ushort* As, ushort* Bs) {
    constexpr int K   = 2048;
    constexpr int NKT = K / 64;

    const int tid  = threadIdx.x;
    const int wv   = tid >> 6, lane = tid & 63;
    const int wr   = wv >> 2,  wc   = wv & 3;
    const int mq   = lane & 15, quad = lane >> 4;
    const int cho  = ((quad ^ (mq & 3)) << 3);

    const int srow = tid >> 2;
    const int cxr  = (((tid & 3) ^ (srow & 3)) << 3);
    const ushort* sA0 = A  + (size_t)(m0 + srow) * K + cxr;
    const ushort* sB0 = Bt + (size_t)(n0 + srow) * K + cxr;
    const ushort* sB1 = sB0 + (size_t)128 * K;
    const int sdo = wv * 512;

    const int arow = wr * 64 + mq;
    const int brow = wc * 64 + mq;

    v4f acc[4][4] = {};

    auto stage = [&](int buf, int kh, int kt) {   // A(1) + B(2) loads per kh
        const int ko = kt * 64 + kh * 32;
        load_lds16(sA0 + ko, As + (buf * 2 + kh) * 4096 + sdo);
        ushort* d = Bs + (buf * 2 + kh) * 8192 + sdo;
        load_lds16(sB0 + ko, d);
        load_lds16(sB1 + ko, d + 4096);
    };
    auto rd4 = [&](v8bf (&r)[4], const ushort* kb, int r0) {
#pragma unroll
        for (int i = 0; i < 4; ++i)
            r[i] = *(const v8bf*)&kb[(r0 + i * 16) * 32 + cho];
    };
    auto mma = [&](const v8bf (&a)[4], const v8bf (&b)[4]) {
#pragma unroll
        for (int i = 0; i < 4; ++i)
#pragma unroll
            for (int nt = 0; nt < 4; ++nt)
                acc[i][nt] = __builtin_amdgcn_mfma_f32_16x16x32_bf16(
                    a[i], b[nt], acc[i][nt], 0, 0, 0);
    };

    stage(0, 0, 0); stage(0, 1, 0);
    vmwait<3>();
    __builtin_amdgcn_s_barrier();
    __builtin_amdgcn_sched_barrier(0);

#pragma unroll 1
    for (int t = 0; t < NKT; ++t) {
        const int p = t & 1, pn = p ^ 1;
        const bool more = (t + 1 < NKT);
        const ushort* a0 = As + p * 8192;
        const ushort* a1 = a0 + 4096;
        const ushort* b0 = Bs + p * 16384;
        const ushort* b1 = b0 + 8192;
        v8bf af[4], bfr[4];

        // kh0 phase
        rd4(af, a0, arow); rd4(bfr, b0, brow);
        if (more) stage(pn, 0, t + 1);
        pbar();
        __builtin_amdgcn_s_setprio(1); mma(af, bfr); __builtin_amdgcn_s_setprio(0);
        if (more) vmwait<3>(); else vmwait<0>();
        pbar();
        // kh1 phase
        rd4(af, a1, arow); rd4(bfr, b1, brow);
        if (more) stage(pn, 1, t + 1);
        pbar();
        __builtin_amdgcn_s_setprio(1); mma(af, bfr); __builtin_amdgcn_s_setprio(0);
        if (more) vmwait<3>();
        pbar();
    }

#pragma unroll
    for (int mt = 0; mt < 4; ++mt) {
        const int r = m0 + wr * 64 + mt * 16 + quad * 4;
#pragma unroll
        for (int nt = 0; nt < 4; ++nt) {
            const int c = n0 + wc * 64 + nt * 16 + mq;
#pragma unroll
            for (int reg = 0; reg < 4; ++reg) {
                if (OUT_BF16)
                    ((ushort*)Cout)[(size_t)(r + reg) * ldc + c] = f2bf(acc[mt][nt][reg]);
                else
                    ((float*)Cout)[(size_t)(r + reg) * ldc + c] = acc[mt][nt][reg];
            }
        }
    }
}

// output projection: d_out[4096][2048] f32 = attn_out * wo_t^T
__global__ __launch_bounds__(512, 2) void gemm_out(
    const ushort* __restrict__ A, const ushort* __restrict__ Bt,
    float* __restrict__ C) {
    __shared__ __align__(16) ushort As[16384];   // 32 KB
    __shared__ __align__(16) ushort Bs[32768];   // 64 KB
    const int w = (blockIdx.x & 7) * 32 + (blockIdx.x >> 3);   // 256 = 8*32
    gemm128_body<false>(A, Bt, C, 2048, (w >> 3) * 128, (w & 7) * 256, As, Bs);
}

// ---------- flash attention v10 (best measured; setprio removed — measured null) ----------
constexpr float SC2 = 0.18033688011f;   // 0.125 * log2(e)
constexpr float MB2 = 14.4269504089f;   // 10 * log2(e)  (fixed softmax max M=10, exact)

template <bool MASK>
__device__ __forceinline__ void attn_compute(
    int kv0, int qrow, int mq, int quad, int lane_lo,
    const ushort* Ks, const ushort* Vs, const v8bf ones,
    const v8bf (&qf)[2][2], v4f (&oacc)[2][4], v4f (&osum)[2]) {
    const bool hi = quad >= 2;
    const int swz = mq & 7;
#pragma unroll
    for (int half = 0; half < 2; ++half) {
        uint32_t pk[2][2][2];
#pragma unroll
        for (int ntl = 0; ntl < 2; ++ntl) {
            const int nt = 2 * half + ntl;
            v4f sacc[2] = {{0.f,0.f,0.f,0.f}, {0.f,0.f,0.f,0.f}};
#pragma unroll
            for (int ks = 0; ks < 2; ++ks) {
                v8bf kb = *(const v8bf*)&Ks[(nt * 16 + mq) * 64 + (((ks << 2) + quad) ^ swz) * 8];
                sacc[0] = __builtin_amdgcn_mfma_f32_16x16x32_bf16(kb, qf[0][ks], sacc[0], 0, 0, 0);
                sacc[1] = __builtin_amdgcn_mfma_f32_16x16x32_bf16(kb, qf[1][ks], sacc[1], 0, 0, 0);
            }
#pragma unroll
            for (int g = 0; g < 2; ++g) {
                float pr[4];
#pragma unroll
                for (int reg = 0; reg < 4; ++reg) {
                    float s = sacc[g][reg];
                    if (MASK) {
                        const int kv = kv0 + nt * 16 + quad * 4 + reg;
                        const int q  = qrow + 16 * g + mq;
                        if (kv > q) s = -3.0e38f;
                    }
                    pr[reg] = __builtin_amdgcn_exp2f(fmaf(s, SC2, -MB2));
                }
                pk[g][ntl][0] = pack2bf(pr[0], pr[1]);
                pk[g][ntl][1] = pack2bf(pr[2], pr[3]);
            }
        }
        v8bf pf[2];
#pragma unroll
        for (int g = 0; g < 2; ++g) {
            uint32_t a0 = __shfl(pk[g][0][0], lane_lo);
            uint32_t b0 = __shfl(pk[g][1][0], lane_lo);
            uint32_t a1 = __shfl(pk[g][0][1], lane_lo);
            uint32_t b1 = __shfl(pk[g][1][1], lane_lo);
            uint32_t a2 = __shfl(pk[g][0][0], lane_lo + 16);
            uint32_t b2 = __shfl(pk[g][1][0], lane_lo + 16);
            uint32_t a3 = __shfl(pk[g][0][1], lane_lo + 16);
            uint32_t b3 = __shfl(pk[g][1][1], lane_lo + 16);
            union { uint32_t d[4]; v8bf v; } u;
            u.d[0] = hi ? b0 : a0;
            u.d[1] = hi ? b1 : a1;
            u.d[2] = hi ? b2 : a2;
            u.d[3] = hi ? b3 : a3;
            pf[g] = u.v;
            osum[g] = __builtin_amdgcn_mfma_f32_16x16x32_bf16(pf[g], ones, osum[g], 0, 0, 0);
        }
#pragma unroll
        for (int hdt = 0; hdt < 4; ++hdt) {
            v8bf vb = *(const v8bf*)&Vs[(hdt * 16 + mq) * 64 + (((half << 2) + quad) ^ swz) * 8];
            oacc[0][hdt] = __builtin_amdgcn_mfma_f32_16x16x32_bf16(pf[0], vb, oacc[0][hdt], 0, 0, 0);
            oacc[1][hdt] = __builtin_amdgcn_mfma_f32_16x16x32_bf16(pf[1], vb, oacc[1][hdt], 0, 0, 0);
        }
    }
}

// qkb: [B*T][2560] bf16 (Q|K); vt: [512][4096] bf16; out: [B*T][2048] bf16
// 256 threads / 4 waves / 128-row q-tiles (32 rows = 2 groups per wave).
// LDS 32 KB dbuf -> 4 blocks/CU (grid = 1024 = 4/CU).
__global__ __launch_bounds__(256, 4) void attn_fwd(
    const ushort* __restrict__ qkb, const ushort* __restrict__ vt,
    ushort* __restrict__ outp) {
    __shared__ __align__(16) ushort Ks[2][4096];   // [buf][64 rows][64 cols], chunk-swizzled
    __shared__ __align__(16) ushort Vs[2][4096];

    const int tid  = threadIdx.x;
    const int wv   = tid >> 6, lane = tid & 63;
    const int mq = lane & 15, quad = lane >> 4;
    const int lane_lo = (quad & 1) * 32 + mq;

    // balanced work assignment: same-CU blocks {i, i+256, i+512, i+768} get
    // qt sets {2j, 2j+1, 15-2j, 14-2j} -> per-CU tile total = 68, constant.
    const int i = blockIdx.x;
    const int u = i & 255, s = i >> 8;
    const int h = u & 31, j = u >> 5;
    const int b = s >> 1;
    const int qt = (s == 0) ? 2 * j
                 : (s == 1) ? 2 * j + 1
                 : (s == 2) ? 15 - 2 * j
                            : 14 - 2 * j;
    const int g = h >> 2;
    const int qb0  = qt * 128;
    const int qrow = qb0 + wv * 32;

    union { ushort u[8]; v8bf v; } one_u;
#pragma unroll
    for (int ii = 0; ii < 8; ++ii) one_u.u[ii] = 0x3F80;
    const v8bf ones = one_u.v;

    v8bf qf[2][2];
#pragma unroll
    for (int gg = 0; gg < 2; ++gg) {
        const ushort* qp = qkb + (size_t)(b * 2048 + qrow + 16 * gg + mq) * 2560 + h * 64 + quad * 8;
        qf[gg][0] = *(const v8bf*)qp;
        qf[gg][1] = *(const v8bf*)(qp + 32);
    }

    v4f oacc[2][4] = {};
    v4f osum[2] = {};

    const ushort* kg = qkb + (size_t)(b * 2048) * 2560 + 2048 + g * 64;
    const ushort* vg = vt + (size_t)(g * 64) * 4096 + b * 2048;

    // staging: LDS dest linear (global_load_lds), swizzle on per-lane GLOBAL chunk
    const int sr = lane >> 3;
    const int gc = (lane & 7) ^ sr;
    const ushort* kb0 = kg + (size_t)(wv * 16 + sr) * 2560 + gc * 8;
    const ushort* kb1 = kb0 + (size_t)8 * 2560;
    const ushort* vb0 = vg + (size_t)(wv * 16 + sr) * 4096 + gc * 8;
    const ushort* vb1 = vb0 + (size_t)8 * 4096;
    const int ldso = wv * 1024;

    const int ntiles = 2 * qt + 2;

    load_lds16(kb0, &Ks[0][ldso]);
    load_lds16(kb1, &Ks[0][ldso + 512]);
    load_lds16(vb0, &Vs[0][ldso]);
    load_lds16(vb1, &Vs[0][ldso + 512]);
    __syncthreads();

#pragma unroll 1
    for (int jt = 0; jt < ntiles; ++jt) {
        const int kv0 = jt * 64;
        const int p = jt & 1;
        if (jt + 1 < ntiles) {   // DMA-prefetch next tile into the other buffer
            const int nk = kv0 + 64;
            load_lds16(kb0 + (size_t)nk * 2560, &Ks[p ^ 1][ldso]);
            load_lds16(kb1 + (size_t)nk * 2560, &Ks[p ^ 1][ldso + 512]);
            load_lds16(vb0 + nk, &Vs[p ^ 1][ldso]);
            load_lds16(vb1 + nk, &Vs[p ^ 1][ldso + 512]);
        }
        // kv0 - qrow multiple of 32 -> both groups active iff kv0 <= qrow;
        // masked iff kv0 + 64 > qrow (exactly one such tile per wave).
        if (kv0 <= qrow) {
            if (kv0 + 64 > qrow)
                attn_compute<true>(kv0, qrow, mq, quad, lane_lo, Ks[p], Vs[p], ones, qf, oacc, osum);
            else
                attn_compute<false>(kv0, qrow, mq, quad, lane_lo, Ks[p], Vs[p], ones, qf, oacc, osum);
        }
        __syncthreads();   // joins waves; compiler's vmcnt(0) drain completes the DMA
    }

    // normalize: osum is in C-layout identical to oacc — no shuffles
#pragma unroll
    for (int gg = 0; gg < 2; ++gg) {
#pragma unroll
        for (int reg = 0; reg < 4; ++reg) {
            const float invr = 1.0f / osum[gg][reg];
            const int rr = qrow + 16 * gg + quad * 4 + reg;
#pragma unroll
            for (int hdt = 0; hdt < 4; ++hdt)
                outp[(size_t)(b * 2048 + rr) * 2048 + h * 64 + hdt * 16 + mq] =
                    f2bf(oacc[gg][hdt][reg] * invr);
        }
    }
}

// ---------- launch ----------
extern "C" void kernel_launch(void* const* d_in, const int* in_sizes, int n_in,
                              void* d_out, int out_size, void* d_ws, size_t ws_size,
                              hipStream_t stream) {
    const float* x  = (const float*)d_in[0];
    const float* Wq = (const float*)d_in[1];
    const float* Wk = (const float*)d_in[2];
    const float* Wv = (const float*)d_in[3];
    const float* Wo = (const float*)d_in[4];

    char* ws = (char*)d_ws;
    ushort* xb    = (ushort*)(ws);                  // [4096][2048] x bf16; later attn output
    ushort* wqk_t = (ushort*)(ws + 16777216);       // [2560][2048]  (rows 0-2559 of wqkv_t)
    ushort* wv_t  = (ushort*)(ws + 27262976);       // [512][2048]   (rows 2560-3071, contiguous!)
    ushort* wo_t  = (ushort*)(ws + 29360128);       // [2048][2048]
    ushort* qkb   = (ushort*)(ws + 37748736);       // [4096][2560]  Q|K
    ushort* vtb   = (ushort*)(ws + 58720256);       // [512][4096]   V^T

    prep_all<<<10752, 256, 0, stream>>>((const float4*)x, xb, Wq, Wk, Wv, Wo,
                                        wqk_t, wv_t, wo_t);
    // wqk_t and wv_t are contiguous -> wqk_t doubles as wqkv_t [3072][2048]
    gemm_qkv<<<256, 512, 0, stream>>>(xb, wqk_t, qkb, vtb);
    attn_fwd<<<1024, 256, 0, stream>>>(qkb, vtb, xb);
    gemm_out<<<256, 512, 0, stream>>>(xb, wo_t, (float*)d_out);
}